// Round 7
// baseline (1171.344 us; speedup 1.0000x reference)
//
#include <hip/hip_runtime.h>

typedef _Float16 h8 __attribute__((ext_vector_type(8)));
typedef _Float16 h4 __attribute__((ext_vector_type(4)));
typedef float f32x4 __attribute__((ext_vector_type(4)));

__device__ __forceinline__ float fsigm(float x) {
    return __builtin_amdgcn_rcpf(1.0f + __expf(-x));
}
// tanh(x) = 1 - 2/(1+e^{2x}) : no abs/copysign, inf-safe (rcp(inf)=0).
__device__ __forceinline__ float ftanh(float x) {
    return 1.0f - 2.0f * __builtin_amdgcn_rcpf(1.0f + __expf(2.0f * x));
}
__device__ __forceinline__ float fexp2(float x) {
    return __builtin_amdgcn_exp2f(x);
}
// LDS-only barrier: drains lgkmcnt, leaves global loads/stores in flight.
__device__ __forceinline__ void lds_barrier() {
    asm volatile("s_waitcnt lgkmcnt(0)\n\ts_barrier" ::: "memory");
}

#define L2E  1.4426950408889634f
#define L2E2 2.8853900817779268f

// ---------------------------------------------------------------------------
// K1: dist[256][8192] = input[256][512] @ akey[8192][512]^T
// MFMA f16 hi/lo. Tile 64m x 64n (512 blocks -> 2/CU for latency hiding).
// ---------------------------------------------------------------------------
__global__ __launch_bounds__(256) void k_distM(const float* __restrict__ A,
                                               const float* __restrict__ Bm,
                                               float* __restrict__ C) {
    __shared__ _Float16 Ah[64][40], Al[64][40];   // [m][k], pad 40
    __shared__ _Float16 Bh[64][40], Bl[64][40];   // [n][k]
    const int n0 = blockIdx.x * 64;
    const int m0 = blockIdx.y * 64;
    const int tid = threadIdx.x;
    const int lane = tid & 63, wv = tid >> 6;
    const int quad = lane >> 4, l15 = lane & 15;
    f32x4 acc[4];
#pragma unroll
    for (int i = 0; i < 4; ++i) acc[i] = (f32x4){0.f, 0.f, 0.f, 0.f};

    for (int kt = 0; kt < 512; kt += 32) {
        __syncthreads();
#pragma unroll
        for (int r = 0; r < 2; ++r) {           // A: 64x32 = 512 float4
            int idx = tid + 256 * r;
            int m = idx >> 3, kq = (idx & 7) * 4;
            float4 v = *(const float4*)&A[(size_t)(m0 + m) * 512 + kt + kq];
            float e[4] = {v.x, v.y, v.z, v.w};
            h4 hi, lo;
#pragma unroll
            for (int j = 0; j < 4; ++j) {
                _Float16 h = (_Float16)e[j];
                hi[j] = h; lo[j] = (_Float16)(e[j] - (float)h);
            }
            *(h4*)&Ah[m][kq] = hi;
            *(h4*)&Al[m][kq] = lo;
        }
#pragma unroll
        for (int r = 0; r < 2; ++r) {           // B: 64x32 = 512 float4
            int idx = tid + 256 * r;
            int n = idx >> 3, kq = (idx & 7) * 4;
            float4 v = *(const float4*)&Bm[(size_t)(n0 + n) * 512 + kt + kq];
            float e[4] = {v.x, v.y, v.z, v.w};
            h4 hi, lo;
#pragma unroll
            for (int j = 0; j < 4; ++j) {
                _Float16 h = (_Float16)e[j];
                hi[j] = h; lo[j] = (_Float16)(e[j] - (float)h);
            }
            *(h4*)&Bh[n][kq] = hi;
            *(h4*)&Bl[n][kq] = lo;
        }
        __syncthreads();
        h8 ah = *(const h8*)&Ah[wv * 16 + l15][quad * 8];
        h8 al = *(const h8*)&Al[wv * 16 + l15][quad * 8];
#pragma unroll
        for (int nt = 0; nt < 4; ++nt) {
            h8 bhf = *(const h8*)&Bh[nt * 16 + l15][quad * 8];
            h8 blf = *(const h8*)&Bl[nt * 16 + l15][quad * 8];
            acc[nt] = __builtin_amdgcn_mfma_f32_16x16x32_f16(ah, bhf, acc[nt], 0, 0, 0);
            acc[nt] = __builtin_amdgcn_mfma_f32_16x16x32_f16(al, bhf, acc[nt], 0, 0, 0);
            acc[nt] = __builtin_amdgcn_mfma_f32_16x16x32_f16(ah, blf, acc[nt], 0, 0, 0);
        }
    }
#pragma unroll
    for (int nt = 0; nt < 4; ++nt)
#pragma unroll
        for (int r = 0; r < 4; ++r)
            C[(size_t)(m0 + wv * 16 + quad * 4 + r) * 8192 + n0 + nt * 16 + l15] = acc[nt][r];
}

// ---------------------------------------------------------------------------
// K2: per-row argmax (first index on ties) -> set 0 -> softmax, in place.
// ---------------------------------------------------------------------------
__global__ __launch_bounds__(512) void k_softmax(float* __restrict__ D) {
    __shared__ float row[8192];
    __shared__ float r1[512];
    __shared__ int   ri[512];
    __shared__ float r2[512];
    const int b = blockIdx.x, tid = threadIdx.x;
    float* dr = D + (size_t)b * 8192;
    for (int i = tid; i < 2048; i += 512)
        *(float4*)&row[i * 4] = *(const float4*)&dr[i * 4];
    __syncthreads();

    float m1 = -INFINITY, m2 = -INFINITY; int i1 = 0x7fffffff;
    for (int i = tid; i < 8192; i += 512) {
        float v = row[i];
        if (v > m1) { m2 = m1; m1 = v; i1 = i; }
        else        { m2 = fmaxf(m2, v); }       // v==m1 duplicate -> m2=m1
    }
    r1[tid] = m1; ri[tid] = i1; r2[tid] = m2;
    __syncthreads();
    for (int s = 256; s > 0; s >>= 1) {
        if (tid < s) {
            float am1 = r1[tid], bm1 = r1[tid + s];
            int   ai1 = ri[tid], bi1 = ri[tid + s];
            float am2 = r2[tid], bm2 = r2[tid + s];
            bool bwins = (bm1 > am1) || (bm1 == am1 && bi1 < ai1);
            float wm1 = bwins ? bm1 : am1;
            int   wi1 = bwins ? bi1 : ai1;
            float lm1 = bwins ? am1 : bm1;       // loser's max (covers dups)
            float wm2 = fmaxf(fmaxf(am2, bm2), lm1);
            r1[tid] = wm1; ri[tid] = wi1; r2[tid] = wm2;
        }
        __syncthreads();
    }
    const int   I1 = ri[0];
    const float M  = fmaxf(r2[0], 0.0f);          // max of modified row
    __syncthreads();

    float ssum = 0.0f;
    for (int i = tid; i < 8192; i += 512) {
        float v = (i == I1) ? 0.0f : row[i];
        float e = __expf(v - M);
        row[i] = e;
        ssum += e;
    }
    r1[tid] = ssum;
    __syncthreads();
    for (int s = 256; s > 0; s >>= 1) {
        if (tid < s) r1[tid] += r1[tid + s];
        __syncthreads();
    }
    const float inv = 1.0f / r1[0];
    for (int i = tid; i < 2048; i += 512) {
        float4 v = *(float4*)&row[i * 4];
        v.x *= inv; v.y *= inv; v.z *= inv; v.w *= inv;
        *(float4*)&dr[i * 4] = v;
    }
}

// ---------------------------------------------------------------------------
// K3: hist[256][544] += a[256][8192] @ aval[8192][544]
// MFMA f16 hi/lo, split-K=16 (576 blocks -> 2.25/CU), tile 64m x 64n.
// Round-7 staging fix: B loads coalesced scalar (64-float runs/instr) and
// b128 LDS writes (bank-uniform: 8 hits/bank/wave = b128 minimum). The old
// scalar f16 writes at 4-row stride were ~8-way conflicted (10.3M/dispatch).
// ---------------------------------------------------------------------------
__global__ __launch_bounds__(256) void k_histM(const float* __restrict__ A,
                                               const float* __restrict__ Bm,
                                               float* __restrict__ C) {
    __shared__ _Float16 Ah[64][40], Al[64][40];   // [m][k]
    __shared__ _Float16 Bh[64][40], Bl[64][40];   // [n][k] (transposed aval)
    const int n0 = blockIdx.x * 64;
    const int m0 = blockIdx.y * 64;
    const int kz = blockIdx.z;
    const int tid = threadIdx.x;
    const int lane = tid & 63, wv = tid >> 6;
    const int quad = lane >> 4, l15 = lane & 15;
    const int bn = tid & 63;                 // B-stage: n within tile
    const int ko = (tid >> 6) * 8;           // B-stage: k offset {0,8,16,24}
    const bool bok = (n0 + bn) < 544;
    f32x4 acc[4];
#pragma unroll
    for (int i = 0; i < 4; ++i) acc[i] = (f32x4){0.f, 0.f, 0.f, 0.f};

    const int k_lo = kz * 512, k_hi = k_lo + 512;
    for (int kt = k_lo; kt < k_hi; kt += 32) {
        __syncthreads();
#pragma unroll
        for (int r = 0; r < 2; ++r) {           // A: 64x32 = 512 float4
            int idx = tid + 256 * r;
            int m = idx >> 3, kq = (idx & 7) * 4;
            float4 v = *(const float4*)&A[(size_t)(m0 + m) * 8192 + kt + kq];
            float e[4] = {v.x, v.y, v.z, v.w};
            h4 hi, lo;
#pragma unroll
            for (int j = 0; j < 4; ++j) {
                _Float16 h = (_Float16)e[j];
                hi[j] = h; lo[j] = (_Float16)(e[j] - (float)h);
            }
            *(h4*)&Ah[m][kq] = hi;
            *(h4*)&Al[m][kq] = lo;
        }
        {                                       // B: aval[32k][64n] -> [n][k]
            float e[8];
#pragma unroll
            for (int j = 0; j < 8; ++j)
                e[j] = bok ? Bm[(size_t)(kt + ko + j) * 544 + n0 + bn] : 0.f;
            h8 hi, lo;
#pragma unroll
            for (int j = 0; j < 8; ++j) {
                _Float16 h = (_Float16)e[j];
                hi[j] = h; lo[j] = (_Float16)(e[j] - (float)h);
            }
            *(h8*)&Bh[bn][ko] = hi;
            *(h8*)&Bl[bn][ko] = lo;
        }
        __syncthreads();
        h8 ah = *(const h8*)&Ah[wv * 16 + l15][quad * 8];
        h8 al = *(const h8*)&Al[wv * 16 + l15][quad * 8];
#pragma unroll
        for (int nt = 0; nt < 4; ++nt) {
            h8 bhf = *(const h8*)&Bh[nt * 16 + l15][quad * 8];
            h8 blf = *(const h8*)&Bl[nt * 16 + l15][quad * 8];
            acc[nt] = __builtin_amdgcn_mfma_f32_16x16x32_f16(ah, bhf, acc[nt], 0, 0, 0);
            acc[nt] = __builtin_amdgcn_mfma_f32_16x16x32_f16(al, bhf, acc[nt], 0, 0, 0);
            acc[nt] = __builtin_amdgcn_mfma_f32_16x16x32_f16(ah, blf, acc[nt], 0, 0, 0);
        }
    }
#pragma unroll
    for (int nt = 0; nt < 4; ++nt)
#pragma unroll
        for (int r = 0; r < 4; ++r) {
            int n = n0 + nt * 16 + l15;
            if (n < 544)
                atomicAdd(&C[(size_t)(m0 + wv * 16 + quad * 4 + r) * 544 + n], acc[nt][r]);
        }
}

// ---------------------------------------------------------------------------
// K4: x[b][t][o] = tanh(b1[o] + W1[o][0]*input[b][t] + sum_j W1[o][1+j]*hist[b][t+j])
// ---------------------------------------------------------------------------
__global__ __launch_bounds__(256) void k_xfeat(const float* __restrict__ inp,
                                               const float* __restrict__ hist,
                                               const float* __restrict__ W1,
                                               const float* __restrict__ b1,
                                               float* __restrict__ X) {
    __shared__ float w[33 * 64];
    __shared__ float bl[64];
    __shared__ float il[128];
    __shared__ float hl[160];
    const int t0 = blockIdx.x * 128;
    const int b  = blockIdx.y;
    const int tid = threadIdx.x;
    for (int idx = tid; idx < 2112; idx += 256) {
        int o = idx / 33, k = idx % 33;
        w[k * 64 + o] = W1[idx];
    }
    if (tid < 64) bl[tid] = b1[tid];
    if (tid < 128) il[tid] = inp[(size_t)b * 512 + t0 + tid];
    for (int i = tid; i < 159; i += 256) hl[i] = hist[(size_t)b * 544 + t0 + i];
    __syncthreads();
    const int o = tid & 63, tq = tid >> 6;
    for (int it = 0; it < 32; ++it) {
        int tl = it * 4 + tq;
        float acc = fmaf(il[tl], w[o], bl[o]);
#pragma unroll
        for (int j = 0; j < 32; ++j)
            acc = fmaf(hl[tl + j], w[(1 + j) * 64 + o], acc);
        X[(size_t)(b * 512 + t0 + tl) * 64 + o] = ftanh(acc);
    }
}

// ---------------------------------------------------------------------------
// Pre-gate GEMM body (MFMA f16 hi/lo), 512 threads, tile 128m x 128n x 32k.
// Register-prefetched staging; lgkm-only barriers keep global loads in flight.
// Weight rows and bias are PRE-SCALED by log2e (2*log2e for gate g) so the
// recurrence decodes gates with raw exp2.
// ---------------------------------------------------------------------------
template <int K>
__device__ __forceinline__ void pregemm_mfma(const float* __restrict__ A,
                                             const float* __restrict__ Bw,
                                             const float* __restrict__ bih,
                                             const float* __restrict__ bhh,
                                             float* __restrict__ C,
                                             int t0, int tcs, int gb, float* sm) {
    _Float16* Ah = (_Float16*)sm;            // [128][40]
    _Float16* Al = Ah + 128 * 40;
    _Float16* Bh = Al + 128 * 40;            // [128][40]
    _Float16* Bl = Bh + 128 * 40;            // total 40 KB of the 80 KB smem
    const int n0 = (gb & 3) * 128;
    const int m0 = (gb >> 2) * 128;
    const int tid = threadIdx.x;
    const int lane = tid & 63, wv = tid >> 6;
    const int quad = lane >> 4, l15 = lane & 15;
    const int tcm = (1 << tcs) - 1;
    const int lr0 = tid >> 3, lr1 = lr0 + 64;    // staged rows (0..127)
    const int kq  = (tid & 7) * 4;               // k quad within 32
    const int gr0 = m0 + lr0, gr1 = m0 + lr1;
    const size_t ar0 = ((size_t)(gr0 >> tcs) * 512 + t0 + (gr0 & tcm)) * K;
    const size_t ar1 = ((size_t)(gr1 >> tcs) * 512 + t0 + (gr1 & tcm)) * K;
    const size_t br0 = (size_t)(n0 + lr0) * K;
    const size_t br1 = (size_t)(n0 + lr1) * K;
    // gate-dependent exp2 prescale for the weight rows
    const float sb0 = (((n0 + lr0) >> 7) == 2) ? L2E2 : L2E;
    const float sb1 = (((n0 + lr1) >> 7) == 2) ? L2E2 : L2E;

    f32x4 acc[8];
#pragma unroll
    for (int i = 0; i < 8; ++i) acc[i] = (f32x4){0.f, 0.f, 0.f, 0.f};

    float4 va0 = *(const float4*)&A[ar0 + kq];
    float4 va1 = *(const float4*)&A[ar1 + kq];
    float4 vb0 = *(const float4*)&Bw[br0 + kq];
    float4 vb1 = *(const float4*)&Bw[br1 + kq];

    for (int kt = 0; kt < K; kt += 32) {
        lds_barrier();                       // prev iter's frag reads done
        {
            float e[4]; h4 hi, lo;
            e[0] = va0.x; e[1] = va0.y; e[2] = va0.z; e[3] = va0.w;
#pragma unroll
            for (int j = 0; j < 4; ++j) {
                _Float16 h = (_Float16)e[j];
                hi[j] = h; lo[j] = (_Float16)(e[j] - (float)h);
            }
            *(h4*)&Ah[lr0 * 40 + kq] = hi; *(h4*)&Al[lr0 * 40 + kq] = lo;
            e[0] = va1.x; e[1] = va1.y; e[2] = va1.z; e[3] = va1.w;
#pragma unroll
            for (int j = 0; j < 4; ++j) {
                _Float16 h = (_Float16)e[j];
                hi[j] = h; lo[j] = (_Float16)(e[j] - (float)h);
            }
            *(h4*)&Ah[lr1 * 40 + kq] = hi; *(h4*)&Al[lr1 * 40 + kq] = lo;
            e[0] = vb0.x * sb0; e[1] = vb0.y * sb0; e[2] = vb0.z * sb0; e[3] = vb0.w * sb0;
#pragma unroll
            for (int j = 0; j < 4; ++j) {
                _Float16 h = (_Float16)e[j];
                hi[j] = h; lo[j] = (_Float16)(e[j] - (float)h);
            }
            *(h4*)&Bh[lr0 * 40 + kq] = hi; *(h4*)&Bl[lr0 * 40 + kq] = lo;
            e[0] = vb1.x * sb1; e[1] = vb1.y * sb1; e[2] = vb1.z * sb1; e[3] = vb1.w * sb1;
#pragma unroll
            for (int j = 0; j < 4; ++j) {
                _Float16 h = (_Float16)e[j];
                hi[j] = h; lo[j] = (_Float16)(e[j] - (float)h);
            }
            *(h4*)&Bh[lr1 * 40 + kq] = hi; *(h4*)&Bl[lr1 * 40 + kq] = lo;
        }
        lds_barrier();                       // writes visible to all waves
        if (kt + 32 < K) {                   // prefetch next k-tile (in flight
            va0 = *(const float4*)&A[ar0 + kt + 32 + kq];    // across MFMA +
            va1 = *(const float4*)&A[ar1 + kt + 32 + kq];    // next barrier)
            vb0 = *(const float4*)&Bw[br0 + kt + 32 + kq];
            vb1 = *(const float4*)&Bw[br1 + kt + 32 + kq];
        }
        h8 ah = *(const h8*)&Ah[(wv * 16 + l15) * 40 + quad * 8];
        h8 al = *(const h8*)&Al[(wv * 16 + l15) * 40 + quad * 8];
#pragma unroll
        for (int nt = 0; nt < 8; ++nt) {
            h8 bhf = *(const h8*)&Bh[(nt * 16 + l15) * 40 + quad * 8];
            h8 blf = *(const h8*)&Bl[(nt * 16 + l15) * 40 + quad * 8];
            acc[nt] = __builtin_amdgcn_mfma_f32_16x16x32_f16(ah, bhf, acc[nt], 0, 0, 0);
            acc[nt] = __builtin_amdgcn_mfma_f32_16x16x32_f16(al, bhf, acc[nt], 0, 0, 0);
            acc[nt] = __builtin_amdgcn_mfma_f32_16x16x32_f16(ah, blf, acc[nt], 0, 0, 0);
        }
    }
#pragma unroll
    for (int nt = 0; nt < 8; ++nt) {
        const int n = n0 + nt * 16 + l15;
        const float sc = ((n >> 7) == 2) ? L2E2 : L2E;
        const float bb = (bih[n] + bhh[n]) * sc;
#pragma unroll
        for (int r = 0; r < 4; ++r)
            C[(size_t)(m0 + wv * 16 + quad * 4 + r) * 512 + n] = acc[nt][r] + bb;
    }
}

// ---------------------------------------------------------------------------
// MFMA LSTM recurrence, TRANSPOSED: A = Whh fragment (resident hi/lo),
// B = h fragment, D rows = gate-units, cols = batch. Thread (wv,quad,l15)
// owns batch=b0+l15 and 4 CONSECUTIVE units wv*16+quad*4+r.
// ---------------------------------------------------------------------------
__device__ __forceinline__ _Float16* hpl(float* sm, int buf, int b) {
    return (_Float16*)sm + ((buf * 16 + b) * 136);  // 272B row stride, 2-way max
}

template <int RB>
__device__ __forceinline__ void rec_step(
        float* sm,
        const h8 (&wh)[4][4], const h8 (&wl)[4][4],
        f32x4 (&pc)[4],                   // consumed now, refilled for t+2
        const float*& pp,                 // points at step t+2's pre-gates
        float*& hob, bool wr, bool last,
        float (&c)[4],
        float* __restrict__ Sh, float* __restrict__ Sc,
        int l15, int quad, int un) {
    // B fragments: h[batch l15][k = q*32 + quad*8 + j]
    const _Float16* hp = hpl(sm, RB, l15);
    h8 hf[4];
#pragma unroll
    for (int q = 0; q < 4; ++q)
        hf[q] = *(const h8*)&hp[q * 32 + quad * 8];

    f32x4 aH[4], aL[4];
#pragma unroll
    for (int g = 0; g < 4; ++g) {
        aH[g] = pc[g];                    // C-seed with pre-gates
        aL[g] = (f32x4){0.f, 0.f, 0.f, 0.f};
    }
    // refill pc for step t+2 (2-step latency window; loads stay in flight
    // across lds_barrier which drains lgkm only)
#pragma unroll
    for (int g = 0; g < 4; ++g)
        pc[g] = *(const f32x4*)(pp + g * 128);
    pp += 512;

#pragma unroll
    for (int q = 0; q < 4; ++q) {
#pragma unroll
        for (int g = 0; g < 4; ++g) {
            aH[g] = __builtin_amdgcn_mfma_f32_16x16x32_f16(wh[g][q], hf[q], aH[g], 0, 0, 0);
            aL[g] = __builtin_amdgcn_mfma_f32_16x16x32_f16(wl[g][q], hf[q], aL[g], 0, 0, 0);
        }
    }

    f32x4 hv;
#pragma unroll
    for (int r = 0; r < 4; ++r) {
        float a0 = aH[0][r] + aL[0][r];
        float a1 = aH[1][r] + aL[1][r];
        float a2 = aH[2][r] + aL[2][r];
        float a3 = aH[3][r] + aL[3][r];
        // pre-acts in log2 domain (i,f,o: *log2e; g: *2log2e)
        float iv = __builtin_amdgcn_rcpf(1.0f + fexp2(-a0));
        float fv = __builtin_amdgcn_rcpf(1.0f + fexp2(-a1));
        float gv = 1.0f - 2.0f * __builtin_amdgcn_rcpf(1.0f + fexp2(a2));
        float ov = __builtin_amdgcn_rcpf(1.0f + fexp2(-a3));
        c[r] = fv * c[r] + iv * gv;
        float th = 1.0f - 2.0f * __builtin_amdgcn_rcpf(1.0f + fexp2(c[r] * L2E2));
        hv[r] = ov * th;
    }
    // h exchange: 4 consecutive f16 units -> one ds_write_b64
    h4 hh;
#pragma unroll
    for (int j = 0; j < 4; ++j) hh[j] = (_Float16)hv[j];
    *(h4*)&hpl(sm, 1 - RB, l15)[un] = hh;
    if (wr) {
        __builtin_nontemporal_store(hv, (f32x4*)hob);
        hob += 128;
    }
    if (last) {
        *(f32x4*)Sh = hv;
        f32x4 cv = {c[0], c[1], c[2], c[3]};
        *(f32x4*)Sc = cv;
    }
    lds_barrier();
}

__device__ __forceinline__ void rec_body(const float* __restrict__ P,
                                         const float* __restrict__ Whh,
                                         float* __restrict__ S,
                                         float* __restrict__ Hout,
                                         int t0, int TC, int blk, float* sm) {
    const int b0   = blk * 16;
    const int tid  = threadIdx.x;
    const int lane = tid & 63;
    const int wv   = tid >> 6;
    const int quad = lane >> 4;
    const int l15  = lane & 15;
    const int un   = wv * 16 + quad * 4;   // first of 4 owned units
    const int nrow = wv * 16 + l15;        // A-fragment row (out-unit)

    // Whh hi/lo fragments, pre-scaled by gate log2e factors (resident regs)
    h8 wh[4][4], wl[4][4];
    const float gs[4] = {L2E, L2E, L2E2, L2E};
#pragma unroll
    for (int g = 0; g < 4; ++g) {
        const float sc = gs[g];
        int n = g * 128 + nrow;
#pragma unroll
        for (int q = 0; q < 4; ++q) {
            int kb = q * 32 + quad * 8;
            const float* wp = &Whh[(size_t)n * 128 + kb];
            float4 w0 = *(const float4*)wp;
            float4 w1 = *(const float4*)(wp + 4);
            float we[8] = {w0.x, w0.y, w0.z, w0.w, w1.x, w1.y, w1.z, w1.w};
#pragma unroll
            for (int j = 0; j < 8; ++j) {
                float w = we[j] * sc;
                _Float16 hi = (_Float16)w;
                wh[g][q][j] = hi;
                wl[g][q][j] = (_Float16)(w - (float)hi);
            }
        }
    }

    // state: h,c for (batch b0+l15, units un..un+3)
    float* Sh = S + (size_t)(b0 + l15) * 128 + un;
    float* Sc = Sh + 32768;
    float4 h0 = *(const float4*)Sh;
    float4 c0 = *(const float4*)Sc;
    float c[4] = {c0.x, c0.y, c0.z, c0.w};
    {
        h4 hh;
        hh[0] = (_Float16)h0.x; hh[1] = (_Float16)h0.y;
        hh[2] = (_Float16)h0.z; hh[3] = (_Float16)h0.w;
        *(h4*)&hpl(sm, 0, l15)[un] = hh;
    }

    const bool wr = (Hout != nullptr);
    float* hob = wr ? (Hout + ((size_t)(b0 + l15) * 512 + t0) * 128 + un) : nullptr;

    // pre-gate stream: ONE pointer, 4 dwordx4 with imm offsets g*512B
    const float* pp = P + (size_t)(b0 + l15) * TC * 512 + un;
    f32x4 pcA[4], pcB[4];
#pragma unroll
    for (int g = 0; g < 4; ++g) pcA[g] = *(const f32x4*)(pp + g * 128);
#pragma unroll
    for (int g = 0; g < 4; ++g) pcB[g] = *(const f32x4*)(pp + 512 + g * 128);
    pp += 1024;                            // points at t=2

    lds_barrier();

    for (int tl = 0; tl < TC; tl += 2) {
        rec_step<0>(sm, wh, wl, pcA, pp, hob, wr, false, c, Sh, Sc, l15, quad, un);
        rec_step<1>(sm, wh, wl, pcB, pp, hob, wr, (tl + 2 == TC), c, Sh, Sc, l15, quad, un);
    }
}

// ---------------------------------------------------------------------------
// K5: fused pipeline stage (multi-launch). Blocks 0-15: rec0 chunk k.
// 16-31: rec1 chunk k-2. Rest: MFMA pre-gate GEMMs (pre0 k+1, pre1 k-1).
// 80 KB LDS -> 1 block/CU: rec blocks own their CUs exclusively.
// ---------------------------------------------------------------------------
__global__ __launch_bounds__(512, 1) void k_fused(
        const float* __restrict__ X,    const float* __restrict__ H0,
        const float* __restrict__ Wih0, const float* __restrict__ Wih1,
        const float* __restrict__ bih0, const float* __restrict__ bhh0,
        const float* __restrict__ bih1, const float* __restrict__ bhh1,
        const float* __restrict__ Whh0, const float* __restrict__ Whh1,
        const float* __restrict__ P0r, float* __restrict__ P0w,
        const float* __restrict__ P1r, float* __restrict__ P1w,
        float* __restrict__ S0, float* __restrict__ S1, float* __restrict__ H0out,
        int tr0, int tr1, int tp0, int tp1,
        int v_rec0, int v_rec1, int v_pre0, int v_pre1,
        int TC, int tcs) {
    __shared__ float smem[20480];   // 80 KB -> 1 block/CU (CU isolation)
    const int bid = blockIdx.x;
    if (bid < 16) {
        if (v_rec0) rec_body(P0r, Whh0, S0, H0out, tr0, TC, bid, smem);
        return;
    }
    if (bid < 32) {
        if (v_rec1) rec_body(P1r, Whh1, S1, nullptr, tr1, TC, bid - 16, smem);
        return;
    }
    int gb = bid - 32;
    const int npre = 8 * TC;        // (256*TC/128) m-tiles * 4 n-tiles
    if (gb < npre) {
        if (v_pre0) pregemm_mfma<64>(X, Wih0, bih0, bhh0, P0w, tp0, tcs, gb, smem);
        return;
    }
    gb -= npre;
    if (v_pre1) pregemm_mfma<128>(H0, Wih1, bih1, bhh1, P1w, tp1, tcs, gb, smem);
}

// ---------------------------------------------------------------------------
// K6: tail head: out = tanh(tanh(h1_last) @ W2^T + b2) @ W3^T + b3
// ---------------------------------------------------------------------------
__global__ __launch_bounds__(64) void k_tail(const float* __restrict__ Hs,
                                             const float* __restrict__ W2,
                                             const float* __restrict__ b2,
                                             const float* __restrict__ W3,
                                             const float* __restrict__ b3,
                                             float* __restrict__ out) {
    __shared__ float last[128], l2s[64];
    const int b = blockIdx.x, tid = threadIdx.x;
    last[tid]      = ftanh(Hs[(size_t)b * 128 + tid]);
    last[tid + 64] = ftanh(Hs[(size_t)b * 128 + 64 + tid]);
    __syncthreads();
    float acc = b2[tid];
#pragma unroll 4
    for (int j = 0; j < 128; ++j) acc = fmaf(W2[(size_t)tid * 128 + j], last[j], acc);
    l2s[tid] = ftanh(acc);
    __syncthreads();
    if (tid < 32) {
        float a2 = b3[tid];
#pragma unroll 4
        for (int o = 0; o < 64; ++o) a2 = fmaf(W3[(size_t)tid * 64 + o], l2s[o], a2);
        out[(size_t)b * 32 + tid] = a2;
    }
}

// ---------------------------------------------------------------------------
extern "C" void kernel_launch(void* const* d_in, const int* in_sizes, int n_in,
                              void* d_out, int out_size, void* d_ws, size_t ws_size,
                              hipStream_t stream) {
    (void)in_sizes; (void)n_in; (void)out_size;
    const float* inp  = (const float*)d_in[0];
    const float* akey = (const float*)d_in[1];
    const float* aval = (const float*)d_in[2];
    const float* W1   = (const float*)d_in[3];
    const float* b1   = (const float*)d_in[4];
    const float* Wih0 = (const float*)d_in[5];
    const float* Whh0 = (const float*)d_in[6];
    const float* bih0 = (const float*)d_in[7];
    const float* bhh0 = (const float*)d_in[8];
    const float* Wih1 = (const float*)d_in[9];
    const float* Whh1 = (const float*)d_in[10];
    const float* bih1 = (const float*)d_in[11];
    const float* bhh1 = (const float*)d_in[12];
    const float* W2   = (const float*)d_in[13];
    const float* b2   = (const float*)d_in[14];
    const float* W3   = (const float*)d_in[15];
    const float* b3   = (const float*)d_in[16];

    float* ws   = (float*)d_ws;
    float* dist = ws;                       // 2,097,152
    float* hist = dist + 2097152;           //   139,264
    float* X    = hist + 139264;            // 8,388,608 + 64 pad
    float* S0   = X + 8388672;              //    65,536 (h then c)
    float* S1   = S0 + 65536;               //    65,536
    float* H0   = S1 + 65536;               // 16,777,216  (h0, [b][512][128])
    float* PB   = H0 + 16777216;            // 4 P buffers

    // TC=16 (round 7): pipeline fill/drain costs 3*TC extra step-times
    // (512+3*TC total rec steps: 560 @TC=16 vs 608 @TC=32); step time is
    // TC-independent, launches are graph-replayed (cheap).
    const int TC = 16, tcs = 4;
    const size_t pchunk = (size_t)256 * TC * 512 + 2048;  // +pad: 2-step
    float* P0b[2] = {PB, PB + pchunk};                    // prefetch overrun
    float* P1b[2] = {PB + 2 * pchunk, PB + 3 * pchunk};
    (void)ws_size;

    k_distM<<<dim3(128, 4), 256, 0, stream>>>(inp, akey, dist);
    k_softmax<<<256, 512, 0, stream>>>(dist);
    hipMemsetAsync(hist, 0, 139264 * 4, stream);
    k_histM<<<dim3(9, 4, 16), 256, 0, stream>>>(dist, aval, hist);
    k_xfeat<<<dim3(4, 256), 256, 0, stream>>>(inp, hist, W1, b1, X);
    hipMemsetAsync(S0, 0, (size_t)2 * 65536 * 4, stream);  // S0+S1 contiguous

    const int NC = 512 / TC;
    const int nblocks = 32 + 16 * TC;   // 32 rec + 8*TC pre0 + 8*TC pre1
    for (int k = -1; k <= NC + 1; ++k) {
        int v_rec0 = (k >= 0 && k < NC);
        int v_rec1 = (k >= 2 && k < NC + 2);
        int v_pre0 = (k + 1 >= 0 && k + 1 < NC);
        int v_pre1 = (k - 1 >= 0 && k - 1 < NC);
        if (!(v_rec0 | v_rec1 | v_pre0 | v_pre1)) continue;
        const float* P0r = P0b[k & 1];
        float*       P0w = P0b[(k + 1) & 1];
        const float* P1r = P1b[k & 1];
        float*       P1w = P1b[(k + 1) & 1];
        k_fused<<<nblocks, 512, 0, stream>>>(
            X, H0, Wih0, Wih1, bih0, bhh0, bih1, bhh1, Whh0, Whh1,
            P0r, P0w, P1r, P1w, S0, S1, H0,
            k * TC, (k - 2) * TC, (k + 1) * TC, (k - 1) * TC,
            v_rec0, v_rec1, v_pre0, v_pre1, TC, tcs);
    }
    k_tail<<<256, 64, 0, stream>>>(S1, W2, b2, W3, b3, (float*)d_out);
}

// Round 8
// 1003.032 us; speedup vs baseline: 1.1678x; 1.1678x over previous
//
#include <hip/hip_runtime.h>

typedef _Float16 h8 __attribute__((ext_vector_type(8)));
typedef _Float16 h4 __attribute__((ext_vector_type(4)));
typedef float f32x4 __attribute__((ext_vector_type(4)));

__device__ __forceinline__ float fsigm(float x) {
    return __builtin_amdgcn_rcpf(1.0f + __expf(-x));
}
// tanh(x) = 1 - 2/(1+e^{2x}) : no abs/copysign, inf-safe (rcp(inf)=0).
__device__ __forceinline__ float ftanh(float x) {
    return 1.0f - 2.0f * __builtin_amdgcn_rcpf(1.0f + __expf(2.0f * x));
}
__device__ __forceinline__ float fexp2(float x) {
    return __builtin_amdgcn_exp2f(x);
}
// LDS-only barrier: drains lgkmcnt, leaves global loads/stores in flight.
__device__ __forceinline__ void lds_barrier() {
    asm volatile("s_waitcnt lgkmcnt(0)\n\ts_barrier" ::: "memory");
}

#define L2E  1.4426950408889634f
#define L2E2 2.8853900817779268f

// ---------------------------------------------------------------------------
// K1: dist[256][8192] = input[256][512] @ akey[8192][512]^T
// MFMA f16 hi/lo, tile 64m x 64n. Round-8: register-prefetched staging with
// lgkm-only barriers (round-7 counters: MfmaUtil 5%, VALUBusy 8%, occ 19% —
// full global-load latency was serialized into each of 16 k-tiles).
// ---------------------------------------------------------------------------
__global__ __launch_bounds__(256) void k_distM(const float* __restrict__ A,
                                               const float* __restrict__ Bm,
                                               float* __restrict__ C) {
    __shared__ _Float16 Ah[64][40], Al[64][40];   // [m][k], pad 40
    __shared__ _Float16 Bh[64][40], Bl[64][40];   // [n][k]
    const int n0 = blockIdx.x * 64;
    const int m0 = blockIdx.y * 64;
    const int tid = threadIdx.x;
    const int lane = tid & 63, wv = tid >> 6;
    const int quad = lane >> 4, l15 = lane & 15;
    f32x4 acc[4];
#pragma unroll
    for (int i = 0; i < 4; ++i) acc[i] = (f32x4){0.f, 0.f, 0.f, 0.f};

    int sm_[2], skq_[2];
    size_t arow[2], brow[2];
#pragma unroll
    for (int r = 0; r < 2; ++r) {
        int idx = tid + 256 * r;
        sm_[r] = idx >> 3; skq_[r] = (idx & 7) * 4;
        arow[r] = (size_t)(m0 + sm_[r]) * 512 + skq_[r];
        brow[r] = (size_t)(n0 + sm_[r]) * 512 + skq_[r];
    }
    float4 va[2], vb[2];
#pragma unroll
    for (int r = 0; r < 2; ++r) {
        va[r] = *(const float4*)&A[arow[r]];
        vb[r] = *(const float4*)&Bm[brow[r]];
    }

    for (int kt = 0; kt < 512; kt += 32) {
        lds_barrier();                        // prev iter's frag reads done
#pragma unroll
        for (int r = 0; r < 2; ++r) {
            float e[4] = {va[r].x, va[r].y, va[r].z, va[r].w};
            h4 hi, lo;
#pragma unroll
            for (int j = 0; j < 4; ++j) {
                _Float16 h = (_Float16)e[j];
                hi[j] = h; lo[j] = (_Float16)(e[j] - (float)h);
            }
            *(h4*)&Ah[sm_[r]][skq_[r]] = hi;
            *(h4*)&Al[sm_[r]][skq_[r]] = lo;
            float f[4] = {vb[r].x, vb[r].y, vb[r].z, vb[r].w};
#pragma unroll
            for (int j = 0; j < 4; ++j) {
                _Float16 h = (_Float16)f[j];
                hi[j] = h; lo[j] = (_Float16)(f[j] - (float)h);
            }
            *(h4*)&Bh[sm_[r]][skq_[r]] = hi;
            *(h4*)&Bl[sm_[r]][skq_[r]] = lo;
        }
        lds_barrier();                        // writes visible to all waves
        if (kt + 32 < 512) {                  // prefetch next k-tile: stays in
#pragma unroll                                // flight across MFMA + barrier
            for (int r = 0; r < 2; ++r) {
                va[r] = *(const float4*)&A[arow[r] + kt + 32];
                vb[r] = *(const float4*)&Bm[brow[r] + kt + 32];
            }
        }
        h8 ah = *(const h8*)&Ah[wv * 16 + l15][quad * 8];
        h8 al = *(const h8*)&Al[wv * 16 + l15][quad * 8];
#pragma unroll
        for (int nt = 0; nt < 4; ++nt) {
            h8 bhf = *(const h8*)&Bh[nt * 16 + l15][quad * 8];
            h8 blf = *(const h8*)&Bl[nt * 16 + l15][quad * 8];
            acc[nt] = __builtin_amdgcn_mfma_f32_16x16x32_f16(ah, bhf, acc[nt], 0, 0, 0);
            acc[nt] = __builtin_amdgcn_mfma_f32_16x16x32_f16(al, bhf, acc[nt], 0, 0, 0);
            acc[nt] = __builtin_amdgcn_mfma_f32_16x16x32_f16(ah, blf, acc[nt], 0, 0, 0);
        }
    }
#pragma unroll
    for (int nt = 0; nt < 4; ++nt)
#pragma unroll
        for (int r = 0; r < 4; ++r)
            C[(size_t)(m0 + wv * 16 + quad * 4 + r) * 8192 + n0 + nt * 16 + l15] = acc[nt][r];
}

// ---------------------------------------------------------------------------
// K2: per-row argmax (first index on ties) -> set 0 -> softmax, in place.
// ---------------------------------------------------------------------------
__global__ __launch_bounds__(512) void k_softmax(float* __restrict__ D) {
    __shared__ float row[8192];
    __shared__ float r1[512];
    __shared__ int   ri[512];
    __shared__ float r2[512];
    const int b = blockIdx.x, tid = threadIdx.x;
    float* dr = D + (size_t)b * 8192;
    for (int i = tid; i < 2048; i += 512)
        *(float4*)&row[i * 4] = *(const float4*)&dr[i * 4];
    __syncthreads();

    float m1 = -INFINITY, m2 = -INFINITY; int i1 = 0x7fffffff;
    for (int i = tid; i < 8192; i += 512) {
        float v = row[i];
        if (v > m1) { m2 = m1; m1 = v; i1 = i; }
        else        { m2 = fmaxf(m2, v); }       // v==m1 duplicate -> m2=m1
    }
    r1[tid] = m1; ri[tid] = i1; r2[tid] = m2;
    __syncthreads();
    for (int s = 256; s > 0; s >>= 1) {
        if (tid < s) {
            float am1 = r1[tid], bm1 = r1[tid + s];
            int   ai1 = ri[tid], bi1 = ri[tid + s];
            float am2 = r2[tid], bm2 = r2[tid + s];
            bool bwins = (bm1 > am1) || (bm1 == am1 && bi1 < ai1);
            float wm1 = bwins ? bm1 : am1;
            int   wi1 = bwins ? bi1 : ai1;
            float lm1 = bwins ? am1 : bm1;       // loser's max (covers dups)
            float wm2 = fmaxf(fmaxf(am2, bm2), lm1);
            r1[tid] = wm1; ri[tid] = wi1; r2[tid] = wm2;
        }
        __syncthreads();
    }
    const int   I1 = ri[0];
    const float M  = fmaxf(r2[0], 0.0f);          // max of modified row
    __syncthreads();

    float ssum = 0.0f;
    for (int i = tid; i < 8192; i += 512) {
        float v = (i == I1) ? 0.0f : row[i];
        float e = __expf(v - M);
        row[i] = e;
        ssum += e;
    }
    r1[tid] = ssum;
    __syncthreads();
    for (int s = 256; s > 0; s >>= 1) {
        if (tid < s) r1[tid] += r1[tid + s];
        __syncthreads();
    }
    const float inv = 1.0f / r1[0];
    for (int i = tid; i < 2048; i += 512) {
        float4 v = *(float4*)&row[i * 4];
        v.x *= inv; v.y *= inv; v.z *= inv; v.w *= inv;
        *(float4*)&dr[i * 4] = v;
    }
}

// ---------------------------------------------------------------------------
// K3: hist[256][544] += a[256][8192] @ aval[8192][544]
// MFMA f16 hi/lo, split-K=16 (576 blocks -> 2.25/CU), tile 64m x 64n.
// B loads coalesced scalar (64-float runs/instr), b128 LDS writes
// (bank-uniform). Old scalar f16 writes were ~8-way conflicted (10.3M).
// ---------------------------------------------------------------------------
__global__ __launch_bounds__(256) void k_histM(const float* __restrict__ A,
                                               const float* __restrict__ Bm,
                                               float* __restrict__ C) {
    __shared__ _Float16 Ah[64][40], Al[64][40];   // [m][k]
    __shared__ _Float16 Bh[64][40], Bl[64][40];   // [n][k] (transposed aval)
    const int n0 = blockIdx.x * 64;
    const int m0 = blockIdx.y * 64;
    const int kz = blockIdx.z;
    const int tid = threadIdx.x;
    const int lane = tid & 63, wv = tid >> 6;
    const int quad = lane >> 4, l15 = lane & 15;
    const int bn = tid & 63;                 // B-stage: n within tile
    const int ko = (tid >> 6) * 8;           // B-stage: k offset {0,8,16,24}
    const bool bok = (n0 + bn) < 544;
    f32x4 acc[4];
#pragma unroll
    for (int i = 0; i < 4; ++i) acc[i] = (f32x4){0.f, 0.f, 0.f, 0.f};

    const int k_lo = kz * 512, k_hi = k_lo + 512;
    for (int kt = k_lo; kt < k_hi; kt += 32) {
        __syncthreads();
#pragma unroll
        for (int r = 0; r < 2; ++r) {           // A: 64x32 = 512 float4
            int idx = tid + 256 * r;
            int m = idx >> 3, kq = (idx & 7) * 4;
            float4 v = *(const float4*)&A[(size_t)(m0 + m) * 8192 + kt + kq];
            float e[4] = {v.x, v.y, v.z, v.w};
            h4 hi, lo;
#pragma unroll
            for (int j = 0; j < 4; ++j) {
                _Float16 h = (_Float16)e[j];
                hi[j] = h; lo[j] = (_Float16)(e[j] - (float)h);
            }
            *(h4*)&Ah[m][kq] = hi;
            *(h4*)&Al[m][kq] = lo;
        }
        {                                       // B: aval[32k][64n] -> [n][k]
            float e[8];
#pragma unroll
            for (int j = 0; j < 8; ++j)
                e[j] = bok ? Bm[(size_t)(kt + ko + j) * 544 + n0 + bn] : 0.f;
            h8 hi, lo;
#pragma unroll
            for (int j = 0; j < 8; ++j) {
                _Float16 h = (_Float16)e[j];
                hi[j] = h; lo[j] = (_Float16)(e[j] - (float)h);
            }
            *(h8*)&Bh[bn][ko] = hi;
            *(h8*)&Bl[bn][ko] = lo;
        }
        __syncthreads();
        h8 ah = *(const h8*)&Ah[wv * 16 + l15][quad * 8];
        h8 al = *(const h8*)&Al[wv * 16 + l15][quad * 8];
#pragma unroll
        for (int nt = 0; nt < 4; ++nt) {
            h8 bhf = *(const h8*)&Bh[nt * 16 + l15][quad * 8];
            h8 blf = *(const h8*)&Bl[nt * 16 + l15][quad * 8];
            acc[nt] = __builtin_amdgcn_mfma_f32_16x16x32_f16(ah, bhf, acc[nt], 0, 0, 0);
            acc[nt] = __builtin_amdgcn_mfma_f32_16x16x32_f16(al, bhf, acc[nt], 0, 0, 0);
            acc[nt] = __builtin_amdgcn_mfma_f32_16x16x32_f16(ah, blf, acc[nt], 0, 0, 0);
        }
    }
#pragma unroll
    for (int nt = 0; nt < 4; ++nt)
#pragma unroll
        for (int r = 0; r < 4; ++r) {
            int n = n0 + nt * 16 + l15;
            if (n < 544)
                atomicAdd(&C[(size_t)(m0 + wv * 16 + quad * 4 + r) * 544 + n], acc[nt][r]);
        }
}

// ---------------------------------------------------------------------------
// K4: x[b][t][o] = tanh(b1[o] + W1[o][0]*input[b][t] + sum_j W1[o][1+j]*hist[b][t+j])
// ---------------------------------------------------------------------------
__global__ __launch_bounds__(256) void k_xfeat(const float* __restrict__ inp,
                                               const float* __restrict__ hist,
                                               const float* __restrict__ W1,
                                               const float* __restrict__ b1,
                                               float* __restrict__ X) {
    __shared__ float w[33 * 64];
    __shared__ float bl[64];
    __shared__ float il[128];
    __shared__ float hl[160];
    const int t0 = blockIdx.x * 128;
    const int b  = blockIdx.y;
    const int tid = threadIdx.x;
    for (int idx = tid; idx < 2112; idx += 256) {
        int o = idx / 33, k = idx % 33;
        w[k * 64 + o] = W1[idx];
    }
    if (tid < 64) bl[tid] = b1[tid];
    if (tid < 128) il[tid] = inp[(size_t)b * 512 + t0 + tid];
    for (int i = tid; i < 159; i += 256) hl[i] = hist[(size_t)b * 544 + t0 + i];
    __syncthreads();
    const int o = tid & 63, tq = tid >> 6;
    for (int it = 0; it < 32; ++it) {
        int tl = it * 4 + tq;
        float acc = fmaf(il[tl], w[o], bl[o]);
#pragma unroll
        for (int j = 0; j < 32; ++j)
            acc = fmaf(hl[tl + j], w[(1 + j) * 64 + o], acc);
        X[(size_t)(b * 512 + t0 + tl) * 64 + o] = ftanh(acc);
    }
}

// ---------------------------------------------------------------------------
// Pre-gate GEMM body (MFMA f16 hi/lo), 512 threads, tile 128m x 128n x 32k.
// Register-prefetched staging; lgkm-only barriers keep global loads in flight.
// Weight rows and bias are PRE-SCALED by log2e (2*log2e for gate g) so the
// recurrence decodes gates with raw exp2.
// ---------------------------------------------------------------------------
template <int K>
__device__ __forceinline__ void pregemm_mfma(const float* __restrict__ A,
                                             const float* __restrict__ Bw,
                                             const float* __restrict__ bih,
                                             const float* __restrict__ bhh,
                                             float* __restrict__ C,
                                             int t0, int tcs, int gb, float* sm) {
    _Float16* Ah = (_Float16*)sm;            // [128][40]
    _Float16* Al = Ah + 128 * 40;
    _Float16* Bh = Al + 128 * 40;            // [128][40]
    _Float16* Bl = Bh + 128 * 40;            // total 40 KB of the 80 KB smem
    const int n0 = (gb & 3) * 128;
    const int m0 = (gb >> 2) * 128;
    const int tid = threadIdx.x;
    const int lane = tid & 63, wv = tid >> 6;
    const int quad = lane >> 4, l15 = lane & 15;
    const int tcm = (1 << tcs) - 1;
    const int lr0 = tid >> 3, lr1 = lr0 + 64;    // staged rows (0..127)
    const int kq  = (tid & 7) * 4;               // k quad within 32
    const int gr0 = m0 + lr0, gr1 = m0 + lr1;
    const size_t ar0 = ((size_t)(gr0 >> tcs) * 512 + t0 + (gr0 & tcm)) * K;
    const size_t ar1 = ((size_t)(gr1 >> tcs) * 512 + t0 + (gr1 & tcm)) * K;
    const size_t br0 = (size_t)(n0 + lr0) * K;
    const size_t br1 = (size_t)(n0 + lr1) * K;
    // gate-dependent exp2 prescale for the weight rows
    const float sb0 = (((n0 + lr0) >> 7) == 2) ? L2E2 : L2E;
    const float sb1 = (((n0 + lr1) >> 7) == 2) ? L2E2 : L2E;

    f32x4 acc[8];
#pragma unroll
    for (int i = 0; i < 8; ++i) acc[i] = (f32x4){0.f, 0.f, 0.f, 0.f};

    float4 va0 = *(const float4*)&A[ar0 + kq];
    float4 va1 = *(const float4*)&A[ar1 + kq];
    float4 vb0 = *(const float4*)&Bw[br0 + kq];
    float4 vb1 = *(const float4*)&Bw[br1 + kq];

    for (int kt = 0; kt < K; kt += 32) {
        lds_barrier();                       // prev iter's frag reads done
        {
            float e[4]; h4 hi, lo;
            e[0] = va0.x; e[1] = va0.y; e[2] = va0.z; e[3] = va0.w;
#pragma unroll
            for (int j = 0; j < 4; ++j) {
                _Float16 h = (_Float16)e[j];
                hi[j] = h; lo[j] = (_Float16)(e[j] - (float)h);
            }
            *(h4*)&Ah[lr0 * 40 + kq] = hi; *(h4*)&Al[lr0 * 40 + kq] = lo;
            e[0] = va1.x; e[1] = va1.y; e[2] = va1.z; e[3] = va1.w;
#pragma unroll
            for (int j = 0; j < 4; ++j) {
                _Float16 h = (_Float16)e[j];
                hi[j] = h; lo[j] = (_Float16)(e[j] - (float)h);
            }
            *(h4*)&Ah[lr1 * 40 + kq] = hi; *(h4*)&Al[lr1 * 40 + kq] = lo;
            e[0] = vb0.x * sb0; e[1] = vb0.y * sb0; e[2] = vb0.z * sb0; e[3] = vb0.w * sb0;
#pragma unroll
            for (int j = 0; j < 4; ++j) {
                _Float16 h = (_Float16)e[j];
                hi[j] = h; lo[j] = (_Float16)(e[j] - (float)h);
            }
            *(h4*)&Bh[lr0 * 40 + kq] = hi; *(h4*)&Bl[lr0 * 40 + kq] = lo;
            e[0] = vb1.x * sb1; e[1] = vb1.y * sb1; e[2] = vb1.z * sb1; e[3] = vb1.w * sb1;
#pragma unroll
            for (int j = 0; j < 4; ++j) {
                _Float16 h = (_Float16)e[j];
                hi[j] = h; lo[j] = (_Float16)(e[j] - (float)h);
            }
            *(h4*)&Bh[lr1 * 40 + kq] = hi; *(h4*)&Bl[lr1 * 40 + kq] = lo;
        }
        lds_barrier();                       // writes visible to all waves
        if (kt + 32 < K) {                   // prefetch next k-tile (in flight
            va0 = *(const float4*)&A[ar0 + kt + 32 + kq];    // across MFMA +
            va1 = *(const float4*)&A[ar1 + kt + 32 + kq];    // next barrier)
            vb0 = *(const float4*)&Bw[br0 + kt + 32 + kq];
            vb1 = *(const float4*)&Bw[br1 + kt + 32 + kq];
        }
        h8 ah = *(const h8*)&Ah[(wv * 16 + l15) * 40 + quad * 8];
        h8 al = *(const h8*)&Al[(wv * 16 + l15) * 40 + quad * 8];
#pragma unroll
        for (int nt = 0; nt < 8; ++nt) {
            h8 bhf = *(const h8*)&Bh[(nt * 16 + l15) * 40 + quad * 8];
            h8 blf = *(const h8*)&Bl[(nt * 16 + l15) * 40 + quad * 8];
            acc[nt] = __builtin_amdgcn_mfma_f32_16x16x32_f16(ah, bhf, acc[nt], 0, 0, 0);
            acc[nt] = __builtin_amdgcn_mfma_f32_16x16x32_f16(al, bhf, acc[nt], 0, 0, 0);
            acc[nt] = __builtin_amdgcn_mfma_f32_16x16x32_f16(ah, blf, acc[nt], 0, 0, 0);
        }
    }
#pragma unroll
    for (int nt = 0; nt < 8; ++nt) {
        const int n = n0 + nt * 16 + l15;
        const float sc = ((n >> 7) == 2) ? L2E2 : L2E;
        const float bb = (bih[n] + bhh[n]) * sc;
#pragma unroll
        for (int r = 0; r < 4; ++r)
            C[(size_t)(m0 + wv * 16 + quad * 4 + r) * 512 + n] = acc[nt][r] + bb;
    }
}

// ---------------------------------------------------------------------------
// MFMA LSTM recurrence, TRANSPOSED: A = Whh fragment (resident hi/lo),
// B = h fragment, D rows = gate-units, cols = batch. Thread (wv,quad,l15)
// owns batch=b0+l15 and 4 CONSECUTIVE units wv*16+quad*4+r.
// ---------------------------------------------------------------------------
__device__ __forceinline__ _Float16* hpl(float* sm, int buf, int b) {
    return (_Float16*)sm + ((buf * 16 + b) * 136);  // 272B row stride, 2-way max
}

template <int RB>
__device__ __forceinline__ void rec_step(
        float* sm,
        const h8 (&wh)[4][4], const h8 (&wl)[4][4],
        f32x4 (&pc)[4],                   // consumed now, refilled for t+2
        const float*& pp,                 // points at step t+2's pre-gates
        float*& hob, bool wr, bool last,
        float (&c)[4],
        float* __restrict__ Sh, float* __restrict__ Sc,
        int l15, int quad, int un) {
    // B fragments: h[batch l15][k = q*32 + quad*8 + j]
    const _Float16* hp = hpl(sm, RB, l15);
    h8 hf[4];
#pragma unroll
    for (int q = 0; q < 4; ++q)
        hf[q] = *(const h8*)&hp[q * 32 + quad * 8];

    f32x4 aH[4], aL[4];
#pragma unroll
    for (int g = 0; g < 4; ++g) {
        aH[g] = pc[g];                    // C-seed with pre-gates
        aL[g] = (f32x4){0.f, 0.f, 0.f, 0.f};
    }
    // refill pc for step t+2 (2-step latency window; loads stay in flight
    // across lds_barrier which drains lgkm only)
#pragma unroll
    for (int g = 0; g < 4; ++g)
        pc[g] = *(const f32x4*)(pp + g * 128);
    pp += 512;

#pragma unroll
    for (int q = 0; q < 4; ++q) {
#pragma unroll
        for (int g = 0; g < 4; ++g) {
            aH[g] = __builtin_amdgcn_mfma_f32_16x16x32_f16(wh[g][q], hf[q], aH[g], 0, 0, 0);
            aL[g] = __builtin_amdgcn_mfma_f32_16x16x32_f16(wl[g][q], hf[q], aL[g], 0, 0, 0);
        }
    }

    f32x4 hv;
#pragma unroll
    for (int r = 0; r < 4; ++r) {
        float a0 = aH[0][r] + aL[0][r];
        float a1 = aH[1][r] + aL[1][r];
        float a2 = aH[2][r] + aL[2][r];
        float a3 = aH[3][r] + aL[3][r];
        // pre-acts in log2 domain (i,f,o: *log2e; g: *2log2e)
        float iv = __builtin_amdgcn_rcpf(1.0f + fexp2(-a0));
        float fv = __builtin_amdgcn_rcpf(1.0f + fexp2(-a1));
        float gv = 1.0f - 2.0f * __builtin_amdgcn_rcpf(1.0f + fexp2(a2));
        float ov = __builtin_amdgcn_rcpf(1.0f + fexp2(-a3));
        c[r] = fv * c[r] + iv * gv;
        float th = 1.0f - 2.0f * __builtin_amdgcn_rcpf(1.0f + fexp2(c[r] * L2E2));
        hv[r] = ov * th;
    }
    // h exchange: 4 consecutive f16 units -> one ds_write_b64
    h4 hh;
#pragma unroll
    for (int j = 0; j < 4; ++j) hh[j] = (_Float16)hv[j];
    *(h4*)&hpl(sm, 1 - RB, l15)[un] = hh;
    if (wr) {
        __builtin_nontemporal_store(hv, (f32x4*)hob);
        hob += 128;
    }
    if (last) {
        *(f32x4*)Sh = hv;
        f32x4 cv = {c[0], c[1], c[2], c[3]};
        *(f32x4*)Sc = cv;
    }
    lds_barrier();
}

__device__ __forceinline__ void rec_body(const float* __restrict__ P,
                                         const float* __restrict__ Whh,
                                         float* __restrict__ S,
                                         float* __restrict__ Hout,
                                         int t0, int TC, int blk, float* sm) {
    const int b0   = blk * 16;
    const int tid  = threadIdx.x;
    const int lane = tid & 63;
    const int wv   = tid >> 6;
    const int quad = lane >> 4;
    const int l15  = lane & 15;
    const int un   = wv * 16 + quad * 4;   // first of 4 owned units
    const int nrow = wv * 16 + l15;        // A-fragment row (out-unit)

    // Whh hi/lo fragments, pre-scaled by gate log2e factors (resident regs)
    h8 wh[4][4], wl[4][4];
    const float gs[4] = {L2E, L2E, L2E2, L2E};
#pragma unroll
    for (int g = 0; g < 4; ++g) {
        const float sc = gs[g];
        int n = g * 128 + nrow;
#pragma unroll
        for (int q = 0; q < 4; ++q) {
            int kb = q * 32 + quad * 8;
            const float* wp = &Whh[(size_t)n * 128 + kb];
            float4 w0 = *(const float4*)wp;
            float4 w1 = *(const float4*)(wp + 4);
            float we[8] = {w0.x, w0.y, w0.z, w0.w, w1.x, w1.y, w1.z, w1.w};
#pragma unroll
            for (int j = 0; j < 8; ++j) {
                float w = we[j] * sc;
                _Float16 hi = (_Float16)w;
                wh[g][q][j] = hi;
                wl[g][q][j] = (_Float16)(w - (float)hi);
            }
        }
    }

    // state: h,c for (batch b0+l15, units un..un+3)
    float* Sh = S + (size_t)(b0 + l15) * 128 + un;
    float* Sc = Sh + 32768;
    float4 h0 = *(const float4*)Sh;
    float4 c0 = *(const float4*)Sc;
    float c[4] = {c0.x, c0.y, c0.z, c0.w};
    {
        h4 hh;
        hh[0] = (_Float16)h0.x; hh[1] = (_Float16)h0.y;
        hh[2] = (_Float16)h0.z; hh[3] = (_Float16)h0.w;
        *(h4*)&hpl(sm, 0, l15)[un] = hh;
    }

    const bool wr = (Hout != nullptr);
    float* hob = wr ? (Hout + ((size_t)(b0 + l15) * 512 + t0) * 128 + un) : nullptr;

    // pre-gate stream: ONE pointer, 4 dwordx4 with imm offsets g*512B
    const float* pp = P + (size_t)(b0 + l15) * TC * 512 + un;
    f32x4 pcA[4], pcB[4];
#pragma unroll
    for (int g = 0; g < 4; ++g) pcA[g] = *(const f32x4*)(pp + g * 128);
#pragma unroll
    for (int g = 0; g < 4; ++g) pcB[g] = *(const f32x4*)(pp + 512 + g * 128);
    pp += 1024;                            // points at t=2

    lds_barrier();

    for (int tl = 0; tl < TC; tl += 2) {
        rec_step<0>(sm, wh, wl, pcA, pp, hob, wr, false, c, Sh, Sc, l15, quad, un);
        rec_step<1>(sm, wh, wl, pcB, pp, hob, wr, (tl + 2 == TC), c, Sh, Sc, l15, quad, un);
    }
}

// ---------------------------------------------------------------------------
// K5: fused pipeline stage (multi-launch). Blocks 0-15: rec0 chunk k.
// 16-31: rec1 chunk k-2. Rest: MFMA pre-gate GEMMs (pre0 k+1, pre1 k-1).
// 80 KB LDS -> 1 block/CU: rec blocks own their CUs exclusively.
// ---------------------------------------------------------------------------
__global__ __launch_bounds__(512, 1) void k_fused(
        const float* __restrict__ X,    const float* __restrict__ H0,
        const float* __restrict__ Wih0, const float* __restrict__ Wih1,
        const float* __restrict__ bih0, const float* __restrict__ bhh0,
        const float* __restrict__ bih1, const float* __restrict__ bhh1,
        const float* __restrict__ Whh0, const float* __restrict__ Whh1,
        const float* __restrict__ P0r, float* __restrict__ P0w,
        const float* __restrict__ P1r, float* __restrict__ P1w,
        float* __restrict__ S0, float* __restrict__ S1, float* __restrict__ H0out,
        int tr0, int tr1, int tp0, int tp1,
        int v_rec0, int v_rec1, int v_pre0, int v_pre1,
        int TC, int tcs) {
    __shared__ float smem[20480];   // 80 KB -> 1 block/CU (CU isolation)
    const int bid = blockIdx.x;
    if (bid < 16) {
        if (v_rec0) rec_body(P0r, Whh0, S0, H0out, tr0, TC, bid, smem);
        return;
    }
    if (bid < 32) {
        if (v_rec1) rec_body(P1r, Whh1, S1, nullptr, tr1, TC, bid - 16, smem);
        return;
    }
    int gb = bid - 32;
    const int npre = 8 * TC;        // (256*TC/128) m-tiles * 4 n-tiles
    if (gb < npre) {
        if (v_pre0) pregemm_mfma<64>(X, Wih0, bih0, bhh0, P0w, tp0, tcs, gb, smem);
        return;
    }
    gb -= npre;
    if (v_pre1) pregemm_mfma<128>(H0, Wih1, bih1, bhh1, P1w, tp1, tcs, gb, smem);
}

// ---------------------------------------------------------------------------
// K6: tail head: out = tanh(tanh(h1_last) @ W2^T + b2) @ W3^T + b3
// ---------------------------------------------------------------------------
__global__ __launch_bounds__(64) void k_tail(const float* __restrict__ Hs,
                                             const float* __restrict__ W2,
                                             const float* __restrict__ b2,
                                             const float* __restrict__ W3,
                                             const float* __restrict__ b3,
                                             float* __restrict__ out) {
    __shared__ float last[128], l2s[64];
    const int b = blockIdx.x, tid = threadIdx.x;
    last[tid]      = ftanh(Hs[(size_t)b * 128 + tid]);
    last[tid + 64] = ftanh(Hs[(size_t)b * 128 + 64 + tid]);
    __syncthreads();
    float acc = b2[tid];
#pragma unroll 4
    for (int j = 0; j < 128; ++j) acc = fmaf(W2[(size_t)tid * 128 + j], last[j], acc);
    l2s[tid] = ftanh(acc);
    __syncthreads();
    if (tid < 32) {
        float a2 = b3[tid];
#pragma unroll 4
        for (int o = 0; o < 64; ++o) a2 = fmaf(W3[(size_t)tid * 64 + o], l2s[o], a2);
        out[(size_t)b * 32 + tid] = a2;
    }
}

// ---------------------------------------------------------------------------
extern "C" void kernel_launch(void* const* d_in, const int* in_sizes, int n_in,
                              void* d_out, int out_size, void* d_ws, size_t ws_size,
                              hipStream_t stream) {
    (void)in_sizes; (void)n_in; (void)out_size;
    const float* inp  = (const float*)d_in[0];
    const float* akey = (const float*)d_in[1];
    const float* aval = (const float*)d_in[2];
    const float* W1   = (const float*)d_in[3];
    const float* b1   = (const float*)d_in[4];
    const float* Wih0 = (const float*)d_in[5];
    const float* Whh0 = (const float*)d_in[6];
    const float* bih0 = (const float*)d_in[7];
    const float* bhh0 = (const float*)d_in[8];
    const float* Wih1 = (const float*)d_in[9];
    const float* Whh1 = (const float*)d_in[10];
    const float* bih1 = (const float*)d_in[11];
    const float* bhh1 = (const float*)d_in[12];
    const float* W2   = (const float*)d_in[13];
    const float* b2   = (const float*)d_in[14];
    const float* W3   = (const float*)d_in[15];
    const float* b3   = (const float*)d_in[16];

    float* ws   = (float*)d_ws;
    float* dist = ws;                       // 2,097,152
    float* hist = dist + 2097152;           //   139,264
    float* X    = hist + 139264;            // 8,388,608 + 64 pad
    float* S0   = X + 8388672;              //    65,536 (h then c)
    float* S1   = S0 + 65536;               //    65,536
    float* H0   = S1 + 65536;               // 16,777,216  (h0, [b][512][128])
    float* PB   = H0 + 16777216;            // 4 P buffers
    const size_t fixed = (size_t)(PB - ws);

    // TC=32 (revert of round-7's TC=16: per-dispatch overhead ~6-9 us made
    // 35 dispatches cost more than the 48 saved fill/drain steps).
    // 4 P buffers of 256*TC*512 + 2048 floats (pad: 2-step prefetch overrun).
    int TC = 16, tcs = 4;
    if ((fixed + 4ull * ((size_t)256 * 32 * 512 + 2048)) * 4 <= ws_size) { TC = 32; tcs = 5; }
    const size_t pchunk = (size_t)256 * TC * 512 + 2048;
    float* P0b[2] = {PB, PB + pchunk};
    float* P1b[2] = {PB + 2 * pchunk, PB + 3 * pchunk};

    k_distM<<<dim3(128, 4), 256, 0, stream>>>(inp, akey, dist);
    k_softmax<<<256, 512, 0, stream>>>(dist);
    hipMemsetAsync(hist, 0, 139264 * 4, stream);
    k_histM<<<dim3(9, 4, 16), 256, 0, stream>>>(dist, aval, hist);
    k_xfeat<<<dim3(4, 256), 256, 0, stream>>>(inp, hist, W1, b1, X);
    hipMemsetAsync(S0, 0, (size_t)2 * 65536 * 4, stream);  // S0+S1 contiguous

    const int NC = 512 / TC;
    const int nblocks = 32 + 16 * TC;   // 32 rec + 8*TC pre0 + 8*TC pre1
    for (int k = -1; k <= NC + 1; ++k) {
        int v_rec0 = (k >= 0 && k < NC);
        int v_rec1 = (k >= 2 && k < NC + 2);
        int v_pre0 = (k + 1 >= 0 && k + 1 < NC);
        int v_pre1 = (k - 1 >= 0 && k - 1 < NC);
        if (!(v_rec0 | v_rec1 | v_pre0 | v_pre1)) continue;
        const float* P0r = P0b[k & 1];
        float*       P0w = P0b[(k + 1) & 1];
        const float* P1r = P1b[k & 1];
        float*       P1w = P1b[(k + 1) & 1];
        k_fused<<<nblocks, 512, 0, stream>>>(
            X, H0, Wih0, Wih1, bih0, bhh0, bih1, bhh1, Whh0, Whh1,
            P0r, P0w, P1r, P1w, S0, S1, H0,
            k * TC, (k - 2) * TC, (k + 1) * TC, (k - 1) * TC,
            v_rec0, v_rec1, v_pre0, v_pre1, TC, tcs);
    }
    k_tail<<<256, 64, 0, stream>>>(S1, W2, b2, W3, b3, (float*)d_out);
}

// Round 9
// 970.610 us; speedup vs baseline: 1.2068x; 1.0334x over previous
//
#include <hip/hip_runtime.h>

typedef _Float16 h8 __attribute__((ext_vector_type(8)));
typedef _Float16 h4 __attribute__((ext_vector_type(4)));
typedef float f32x4 __attribute__((ext_vector_type(4)));

__device__ __forceinline__ float fsigm(float x) {
    return __builtin_amdgcn_rcpf(1.0f + __expf(-x));
}
// tanh(x) = 1 - 2/(1+e^{2x}) : no abs/copysign, inf-safe (rcp(inf)=0).
__device__ __forceinline__ float ftanh(float x) {
    return 1.0f - 2.0f * __builtin_amdgcn_rcpf(1.0f + __expf(2.0f * x));
}
__device__ __forceinline__ float fexp2(float x) {
    return __builtin_amdgcn_exp2f(x);
}
// LDS-only barrier: drains lgkmcnt, leaves global loads/stores in flight.
__device__ __forceinline__ void lds_barrier() {
    asm volatile("s_waitcnt lgkmcnt(0)\n\ts_barrier" ::: "memory");
}

#define L2E  1.4426950408889634f
#define L2E2 2.8853900817779268f

// ---------------------------------------------------------------------------
// K1: dist[256][8192] = input[256][512] @ akey[8192][512]^T
// MFMA f16 hi/lo, tile 64m x 64n, register-prefetched staging + lgkm-only
// barriers (round-8: latency no longer serialized per k-tile).
// ---------------------------------------------------------------------------
__global__ __launch_bounds__(256) void k_distM(const float* __restrict__ A,
                                               const float* __restrict__ Bm,
                                               float* __restrict__ C) {
    __shared__ _Float16 Ah[64][40], Al[64][40];   // [m][k], pad 40
    __shared__ _Float16 Bh[64][40], Bl[64][40];   // [n][k]
    const int n0 = blockIdx.x * 64;
    const int m0 = blockIdx.y * 64;
    const int tid = threadIdx.x;
    const int lane = tid & 63, wv = tid >> 6;
    const int quad = lane >> 4, l15 = lane & 15;
    f32x4 acc[4];
#pragma unroll
    for (int i = 0; i < 4; ++i) acc[i] = (f32x4){0.f, 0.f, 0.f, 0.f};

    int sm_[2], skq_[2];
    size_t arow[2], brow[2];
#pragma unroll
    for (int r = 0; r < 2; ++r) {
        int idx = tid + 256 * r;
        sm_[r] = idx >> 3; skq_[r] = (idx & 7) * 4;
        arow[r] = (size_t)(m0 + sm_[r]) * 512 + skq_[r];
        brow[r] = (size_t)(n0 + sm_[r]) * 512 + skq_[r];
    }
    float4 va[2], vb[2];
#pragma unroll
    for (int r = 0; r < 2; ++r) {
        va[r] = *(const float4*)&A[arow[r]];
        vb[r] = *(const float4*)&Bm[brow[r]];
    }

    for (int kt = 0; kt < 512; kt += 32) {
        lds_barrier();                        // prev iter's frag reads done
#pragma unroll
        for (int r = 0; r < 2; ++r) {
            float e[4] = {va[r].x, va[r].y, va[r].z, va[r].w};
            h4 hi, lo;
#pragma unroll
            for (int j = 0; j < 4; ++j) {
                _Float16 h = (_Float16)e[j];
                hi[j] = h; lo[j] = (_Float16)(e[j] - (float)h);
            }
            *(h4*)&Ah[sm_[r]][skq_[r]] = hi;
            *(h4*)&Al[sm_[r]][skq_[r]] = lo;
            float f[4] = {vb[r].x, vb[r].y, vb[r].z, vb[r].w};
#pragma unroll
            for (int j = 0; j < 4; ++j) {
                _Float16 h = (_Float16)f[j];
                hi[j] = h; lo[j] = (_Float16)(f[j] - (float)h);
            }
            *(h4*)&Bh[sm_[r]][skq_[r]] = hi;
            *(h4*)&Bl[sm_[r]][skq_[r]] = lo;
        }
        lds_barrier();                        // writes visible to all waves
        if (kt + 32 < 512) {                  // prefetch next k-tile: stays in
#pragma unroll                                // flight across MFMA + barrier
            for (int r = 0; r < 2; ++r) {
                va[r] = *(const float4*)&A[arow[r] + kt + 32];
                vb[r] = *(const float4*)&Bm[brow[r] + kt + 32];
            }
        }
        h8 ah = *(const h8*)&Ah[wv * 16 + l15][quad * 8];
        h8 al = *(const h8*)&Al[wv * 16 + l15][quad * 8];
#pragma unroll
        for (int nt = 0; nt < 4; ++nt) {
            h8 bhf = *(const h8*)&Bh[nt * 16 + l15][quad * 8];
            h8 blf = *(const h8*)&Bl[nt * 16 + l15][quad * 8];
            acc[nt] = __builtin_amdgcn_mfma_f32_16x16x32_f16(ah, bhf, acc[nt], 0, 0, 0);
            acc[nt] = __builtin_amdgcn_mfma_f32_16x16x32_f16(al, bhf, acc[nt], 0, 0, 0);
            acc[nt] = __builtin_amdgcn_mfma_f32_16x16x32_f16(ah, blf, acc[nt], 0, 0, 0);
        }
    }
#pragma unroll
    for (int nt = 0; nt < 4; ++nt)
#pragma unroll
        for (int r = 0; r < 4; ++r)
            C[(size_t)(m0 + wv * 16 + quad * 4 + r) * 8192 + n0 + nt * 16 + l15] = acc[nt][r];
}

// ---------------------------------------------------------------------------
// K2: per-row argmax (first index on ties) -> set 0 -> softmax, in place.
// ---------------------------------------------------------------------------
__global__ __launch_bounds__(512) void k_softmax(float* __restrict__ D) {
    __shared__ float row[8192];
    __shared__ float r1[512];
    __shared__ int   ri[512];
    __shared__ float r2[512];
    const int b = blockIdx.x, tid = threadIdx.x;
    float* dr = D + (size_t)b * 8192;
    for (int i = tid; i < 2048; i += 512)
        *(float4*)&row[i * 4] = *(const float4*)&dr[i * 4];
    __syncthreads();

    float m1 = -INFINITY, m2 = -INFINITY; int i1 = 0x7fffffff;
    for (int i = tid; i < 8192; i += 512) {
        float v = row[i];
        if (v > m1) { m2 = m1; m1 = v; i1 = i; }
        else        { m2 = fmaxf(m2, v); }       // v==m1 duplicate -> m2=m1
    }
    r1[tid] = m1; ri[tid] = i1; r2[tid] = m2;
    __syncthreads();
    for (int s = 256; s > 0; s >>= 1) {
        if (tid < s) {
            float am1 = r1[tid], bm1 = r1[tid + s];
            int   ai1 = ri[tid], bi1 = ri[tid + s];
            float am2 = r2[tid], bm2 = r2[tid + s];
            bool bwins = (bm1 > am1) || (bm1 == am1 && bi1 < ai1);
            float wm1 = bwins ? bm1 : am1;
            int   wi1 = bwins ? bi1 : ai1;
            float lm1 = bwins ? am1 : bm1;       // loser's max (covers dups)
            float wm2 = fmaxf(fmaxf(am2, bm2), lm1);
            r1[tid] = wm1; ri[tid] = wi1; r2[tid] = wm2;
        }
        __syncthreads();
    }
    const int   I1 = ri[0];
    const float M  = fmaxf(r2[0], 0.0f);          // max of modified row
    __syncthreads();

    float ssum = 0.0f;
    for (int i = tid; i < 8192; i += 512) {
        float v = (i == I1) ? 0.0f : row[i];
        float e = __expf(v - M);
        row[i] = e;
        ssum += e;
    }
    r1[tid] = ssum;
    __syncthreads();
    for (int s = 256; s > 0; s >>= 1) {
        if (tid < s) r1[tid] += r1[tid + s];
        __syncthreads();
    }
    const float inv = 1.0f / r1[0];
    for (int i = tid; i < 2048; i += 512) {
        float4 v = *(float4*)&row[i * 4];
        v.x *= inv; v.y *= inv; v.z *= inv; v.w *= inv;
        *(float4*)&dr[i * 4] = v;
    }
}

// ---------------------------------------------------------------------------
// K3: hist[256][544] += a[256][8192] @ aval[8192][544]
// MFMA f16 hi/lo, split-K=16 (576 blocks -> 2.25/CU), tile 64m x 64n.
// B loads coalesced scalar (64-float runs/instr), b128 LDS writes.
// ---------------------------------------------------------------------------
__global__ __launch_bounds__(256) void k_histM(const float* __restrict__ A,
                                               const float* __restrict__ Bm,
                                               float* __restrict__ C) {
    __shared__ _Float16 Ah[64][40], Al[64][40];   // [m][k]
    __shared__ _Float16 Bh[64][40], Bl[64][40];   // [n][k] (transposed aval)
    const int n0 = blockIdx.x * 64;
    const int m0 = blockIdx.y * 64;
    const int kz = blockIdx.z;
    const int tid = threadIdx.x;
    const int lane = tid & 63, wv = tid >> 6;
    const int quad = lane >> 4, l15 = lane & 15;
    const int bn = tid & 63;                 // B-stage: n within tile
    const int ko = (tid >> 6) * 8;           // B-stage: k offset {0,8,16,24}
    const bool bok = (n0 + bn) < 544;
    f32x4 acc[4];
#pragma unroll
    for (int i = 0; i < 4; ++i) acc[i] = (f32x4){0.f, 0.f, 0.f, 0.f};

    const int k_lo = kz * 512, k_hi = k_lo + 512;
    for (int kt = k_lo; kt < k_hi; kt += 32) {
        __syncthreads();
#pragma unroll
        for (int r = 0; r < 2; ++r) {           // A: 64x32 = 512 float4
            int idx = tid + 256 * r;
            int m = idx >> 3, kq = (idx & 7) * 4;
            float4 v = *(const float4*)&A[(size_t)(m0 + m) * 8192 + kt + kq];
            float e[4] = {v.x, v.y, v.z, v.w};
            h4 hi, lo;
#pragma unroll
            for (int j = 0; j < 4; ++j) {
                _Float16 h = (_Float16)e[j];
                hi[j] = h; lo[j] = (_Float16)(e[j] - (float)h);
            }
            *(h4*)&Ah[m][kq] = hi;
            *(h4*)&Al[m][kq] = lo;
        }
        {                                       // B: aval[32k][64n] -> [n][k]
            float e[8];
#pragma unroll
            for (int j = 0; j < 8; ++j)
                e[j] = bok ? Bm[(size_t)(kt + ko + j) * 544 + n0 + bn] : 0.f;
            h8 hi, lo;
#pragma unroll
            for (int j = 0; j < 8; ++j) {
                _Float16 h = (_Float16)e[j];
                hi[j] = h; lo[j] = (_Float16)(e[j] - (float)h);
            }
            *(h8*)&Bh[bn][ko] = hi;
            *(h8*)&Bl[bn][ko] = lo;
        }
        __syncthreads();
        h8 ah = *(const h8*)&Ah[wv * 16 + l15][quad * 8];
        h8 al = *(const h8*)&Al[wv * 16 + l15][quad * 8];
#pragma unroll
        for (int nt = 0; nt < 4; ++nt) {
            h8 bhf = *(const h8*)&Bh[nt * 16 + l15][quad * 8];
            h8 blf = *(const h8*)&Bl[nt * 16 + l15][quad * 8];
            acc[nt] = __builtin_amdgcn_mfma_f32_16x16x32_f16(ah, bhf, acc[nt], 0, 0, 0);
            acc[nt] = __builtin_amdgcn_mfma_f32_16x16x32_f16(al, bhf, acc[nt], 0, 0, 0);
            acc[nt] = __builtin_amdgcn_mfma_f32_16x16x32_f16(ah, blf, acc[nt], 0, 0, 0);
        }
    }
#pragma unroll
    for (int nt = 0; nt < 4; ++nt)
#pragma unroll
        for (int r = 0; r < 4; ++r) {
            int n = n0 + nt * 16 + l15;
            if (n < 544)
                atomicAdd(&C[(size_t)(m0 + wv * 16 + quad * 4 + r) * 544 + n], acc[nt][r]);
        }
}

// ---------------------------------------------------------------------------
// K4: x[b][t][o] = tanh(b1[o] + W1[o][0]*input[b][t] + sum_j W1[o][1+j]*hist[b][t+j])
// ---------------------------------------------------------------------------
__global__ __launch_bounds__(256) void k_xfeat(const float* __restrict__ inp,
                                               const float* __restrict__ hist,
                                               const float* __restrict__ W1,
                                               const float* __restrict__ b1,
                                               float* __restrict__ X) {
    __shared__ float w[33 * 64];
    __shared__ float bl[64];
    __shared__ float il[128];
    __shared__ float hl[160];
    const int t0 = blockIdx.x * 128;
    const int b  = blockIdx.y;
    const int tid = threadIdx.x;
    for (int idx = tid; idx < 2112; idx += 256) {
        int o = idx / 33, k = idx % 33;
        w[k * 64 + o] = W1[idx];
    }
    if (tid < 64) bl[tid] = b1[tid];
    if (tid < 128) il[tid] = inp[(size_t)b * 512 + t0 + tid];
    for (int i = tid; i < 159; i += 256) hl[i] = hist[(size_t)b * 544 + t0 + i];
    __syncthreads();
    const int o = tid & 63, tq = tid >> 6;
    for (int it = 0; it < 32; ++it) {
        int tl = it * 4 + tq;
        float acc = fmaf(il[tl], w[o], bl[o]);
#pragma unroll
        for (int j = 0; j < 32; ++j)
            acc = fmaf(hl[tl + j], w[(1 + j) * 64 + o], acc);
        X[(size_t)(b * 512 + t0 + tl) * 64 + o] = ftanh(acc);
    }
}

// ---------------------------------------------------------------------------
// Pre-gate GEMM body (MFMA f16 hi/lo), 512 threads, tile 128m x 128n x 32k.
// Register-prefetched staging; lgkm-only barriers keep global loads in flight.
// Weight rows and bias are PRE-SCALED by log2e (2*log2e for gate g) so the
// recurrence decodes gates with raw exp2.
// ---------------------------------------------------------------------------
template <int K>
__device__ __forceinline__ void pregemm_mfma(const float* __restrict__ A,
                                             const float* __restrict__ Bw,
                                             const float* __restrict__ bih,
                                             const float* __restrict__ bhh,
                                             float* __restrict__ C,
                                             int t0, int tcs, int gb, float* sm) {
    _Float16* Ah = (_Float16*)sm;            // [128][40]
    _Float16* Al = Ah + 128 * 40;
    _Float16* Bh = Al + 128 * 40;            // [128][40]
    _Float16* Bl = Bh + 128 * 40;            // total 40 KB of the 80 KB smem
    const int n0 = (gb & 3) * 128;
    const int m0 = (gb >> 2) * 128;
    const int tid = threadIdx.x;
    const int lane = tid & 63, wv = tid >> 6;
    const int quad = lane >> 4, l15 = lane & 15;
    const int tcm = (1 << tcs) - 1;
    const int lr0 = tid >> 3, lr1 = lr0 + 64;    // staged rows (0..127)
    const int kq  = (tid & 7) * 4;               // k quad within 32
    const int gr0 = m0 + lr0, gr1 = m0 + lr1;
    const size_t ar0 = ((size_t)(gr0 >> tcs) * 512 + t0 + (gr0 & tcm)) * K;
    const size_t ar1 = ((size_t)(gr1 >> tcs) * 512 + t0 + (gr1 & tcm)) * K;
    const size_t br0 = (size_t)(n0 + lr0) * K;
    const size_t br1 = (size_t)(n0 + lr1) * K;
    // gate-dependent exp2 prescale for the weight rows
    const float sb0 = (((n0 + lr0) >> 7) == 2) ? L2E2 : L2E;
    const float sb1 = (((n0 + lr1) >> 7) == 2) ? L2E2 : L2E;

    f32x4 acc[8];
#pragma unroll
    for (int i = 0; i < 8; ++i) acc[i] = (f32x4){0.f, 0.f, 0.f, 0.f};

    float4 va0 = *(const float4*)&A[ar0 + kq];
    float4 va1 = *(const float4*)&A[ar1 + kq];
    float4 vb0 = *(const float4*)&Bw[br0 + kq];
    float4 vb1 = *(const float4*)&Bw[br1 + kq];

    for (int kt = 0; kt < K; kt += 32) {
        lds_barrier();                       // prev iter's frag reads done
        {
            float e[4]; h4 hi, lo;
            e[0] = va0.x; e[1] = va0.y; e[2] = va0.z; e[3] = va0.w;
#pragma unroll
            for (int j = 0; j < 4; ++j) {
                _Float16 h = (_Float16)e[j];
                hi[j] = h; lo[j] = (_Float16)(e[j] - (float)h);
            }
            *(h4*)&Ah[lr0 * 40 + kq] = hi; *(h4*)&Al[lr0 * 40 + kq] = lo;
            e[0] = va1.x; e[1] = va1.y; e[2] = va1.z; e[3] = va1.w;
#pragma unroll
            for (int j = 0; j < 4; ++j) {
                _Float16 h = (_Float16)e[j];
                hi[j] = h; lo[j] = (_Float16)(e[j] - (float)h);
            }
            *(h4*)&Ah[lr1 * 40 + kq] = hi; *(h4*)&Al[lr1 * 40 + kq] = lo;
            e[0] = vb0.x * sb0; e[1] = vb0.y * sb0; e[2] = vb0.z * sb0; e[3] = vb0.w * sb0;
#pragma unroll
            for (int j = 0; j < 4; ++j) {
                _Float16 h = (_Float16)e[j];
                hi[j] = h; lo[j] = (_Float16)(e[j] - (float)h);
            }
            *(h4*)&Bh[lr0 * 40 + kq] = hi; *(h4*)&Bl[lr0 * 40 + kq] = lo;
            e[0] = vb1.x * sb1; e[1] = vb1.y * sb1; e[2] = vb1.z * sb1; e[3] = vb1.w * sb1;
#pragma unroll
            for (int j = 0; j < 4; ++j) {
                _Float16 h = (_Float16)e[j];
                hi[j] = h; lo[j] = (_Float16)(e[j] - (float)h);
            }
            *(h4*)&Bh[lr1 * 40 + kq] = hi; *(h4*)&Bl[lr1 * 40 + kq] = lo;
        }
        lds_barrier();                       // writes visible to all waves
        if (kt + 32 < K) {                   // prefetch next k-tile (in flight
            va0 = *(const float4*)&A[ar0 + kt + 32 + kq];    // across MFMA +
            va1 = *(const float4*)&A[ar1 + kt + 32 + kq];    // next barrier)
            vb0 = *(const float4*)&Bw[br0 + kt + 32 + kq];
            vb1 = *(const float4*)&Bw[br1 + kt + 32 + kq];
        }
        h8 ah = *(const h8*)&Ah[(wv * 16 + l15) * 40 + quad * 8];
        h8 al = *(const h8*)&Al[(wv * 16 + l15) * 40 + quad * 8];
#pragma unroll
        for (int nt = 0; nt < 8; ++nt) {
            h8 bhf = *(const h8*)&Bh[(nt * 16 + l15) * 40 + quad * 8];
            h8 blf = *(const h8*)&Bl[(nt * 16 + l15) * 40 + quad * 8];
            acc[nt] = __builtin_amdgcn_mfma_f32_16x16x32_f16(ah, bhf, acc[nt], 0, 0, 0);
            acc[nt] = __builtin_amdgcn_mfma_f32_16x16x32_f16(al, bhf, acc[nt], 0, 0, 0);
            acc[nt] = __builtin_amdgcn_mfma_f32_16x16x32_f16(ah, blf, acc[nt], 0, 0, 0);
        }
    }
#pragma unroll
    for (int nt = 0; nt < 8; ++nt) {
        const int n = n0 + nt * 16 + l15;
        const float sc = ((n >> 7) == 2) ? L2E2 : L2E;
        const float bb = (bih[n] + bhh[n]) * sc;
#pragma unroll
        for (int r = 0; r < 4; ++r)
            C[(size_t)(m0 + wv * 16 + quad * 4 + r) * 512 + n] = acc[nt][r] + bb;
    }
}

// ---------------------------------------------------------------------------
// MFMA LSTM recurrence, TRANSPOSED. Round-9:
//  - Whh single f16 plane (wl dropped): h is already f16-rounded, so W-lo
//    bought precision below the existing noise floor (round-4 evidence:
//    dropping h-lo left absmax bit-identical). 32 -> 16 MFMA/step, -16 adds,
//    -64 live VGPRs.
//  - 3-rcp gate decode: i*g = (C-1)/[(1+C)(1+A)], h = (E-1)/[(1+E)(1+D)]
//    (A=e^-i', B=e^-f', C=e^2g', D=e^-o', E=e^2c). 5 rcp -> 3 rcp/unit:
//    40 -> 32 trans ops/thread/step. Overflow-safe for |preact| < 44.
// ---------------------------------------------------------------------------
__device__ __forceinline__ _Float16* hpl(float* sm, int buf, int b) {
    return (_Float16*)sm + ((buf * 16 + b) * 136);  // 272B row stride, 2-way max
}

template <int RB>
__device__ __forceinline__ void rec_step(
        float* sm,
        const h8 (&wh)[4][4],
        f32x4 (&pc)[4],                   // consumed now, refilled for t+2
        const float*& pp,                 // points at step t+2's pre-gates
        float*& hob, bool wr, bool last,
        float (&c)[4],
        float* __restrict__ Sh, float* __restrict__ Sc,
        int l15, int quad, int un) {
    // B fragments: h[batch l15][k = q*32 + quad*8 + j]
    const _Float16* hp = hpl(sm, RB, l15);
    h8 hf[4];
#pragma unroll
    for (int q = 0; q < 4; ++q)
        hf[q] = *(const h8*)&hp[q * 32 + quad * 8];

    f32x4 aH[4];
#pragma unroll
    for (int g = 0; g < 4; ++g) aH[g] = pc[g];   // C-seed with pre-gates
    // refill pc for step t+2 (2-step latency window; loads stay in flight
    // across lds_barrier which drains lgkm only)
#pragma unroll
    for (int g = 0; g < 4; ++g)
        pc[g] = *(const f32x4*)(pp + g * 128);
    pp += 512;

#pragma unroll
    for (int q = 0; q < 4; ++q)
#pragma unroll
        for (int g = 0; g < 4; ++g)
            aH[g] = __builtin_amdgcn_mfma_f32_16x16x32_f16(wh[g][q], hf[q], aH[g], 0, 0, 0);

    f32x4 hv;
#pragma unroll
    for (int r = 0; r < 4; ++r) {
        // pre-acts in log2 domain (i,f,o: *log2e; g: *2log2e)
        float A = fexp2(-aH[0][r]);              // e^{-i'}
        float B = fexp2(-aH[1][r]);              // e^{-f'}
        float Cv = fexp2(aH[2][r]);              // e^{2g'}
        float D = fexp2(-aH[3][r]);              // e^{-o'}
        float fv = __builtin_amdgcn_rcpf(1.0f + B);
        float ig = (Cv - 1.0f) *
                   __builtin_amdgcn_rcpf((1.0f + Cv) * (1.0f + A));
        c[r] = fmaf(c[r], fv, ig);
        float E = fexp2(c[r] * L2E2);            // e^{2c}
        hv[r] = (E - 1.0f) *
                __builtin_amdgcn_rcpf((1.0f + E) * (1.0f + D));
    }
    // h exchange: 4 consecutive f16 units -> one ds_write_b64
    h4 hh;
#pragma unroll
    for (int j = 0; j < 4; ++j) hh[j] = (_Float16)hv[j];
    *(h4*)&hpl(sm, 1 - RB, l15)[un] = hh;
    if (wr) {
        __builtin_nontemporal_store(hv, (f32x4*)hob);
        hob += 128;
    }
    if (last) {
        *(f32x4*)Sh = hv;
        f32x4 cv = {c[0], c[1], c[2], c[3]};
        *(f32x4*)Sc = cv;
    }
    lds_barrier();
}

__device__ __forceinline__ void rec_body(const float* __restrict__ P,
                                         const float* __restrict__ Whh,
                                         float* __restrict__ S,
                                         float* __restrict__ Hout,
                                         int t0, int TC, int blk, float* sm) {
    const int b0   = blk * 16;
    const int tid  = threadIdx.x;
    const int lane = tid & 63;
    const int wv   = tid >> 6;
    const int quad = lane >> 4;
    const int l15  = lane & 15;
    const int un   = wv * 16 + quad * 4;   // first of 4 owned units
    const int nrow = wv * 16 + l15;        // A-fragment row (out-unit)

    // Whh f16 fragments, pre-scaled by gate log2e factors (resident regs)
    h8 wh[4][4];
    const float gs[4] = {L2E, L2E, L2E2, L2E};
#pragma unroll
    for (int g = 0; g < 4; ++g) {
        const float sc = gs[g];
        int n = g * 128 + nrow;
#pragma unroll
        for (int q = 0; q < 4; ++q) {
            int kb = q * 32 + quad * 8;
            const float* wp = &Whh[(size_t)n * 128 + kb];
            float4 w0 = *(const float4*)wp;
            float4 w1 = *(const float4*)(wp + 4);
            float we[8] = {w0.x, w0.y, w0.z, w0.w, w1.x, w1.y, w1.z, w1.w};
#pragma unroll
            for (int j = 0; j < 8; ++j)
                wh[g][q][j] = (_Float16)(we[j] * sc);
        }
    }

    // state: h,c for (batch b0+l15, units un..un+3)
    float* Sh = S + (size_t)(b0 + l15) * 128 + un;
    float* Sc = Sh + 32768;
    float4 h0 = *(const float4*)Sh;
    float4 c0 = *(const float4*)Sc;
    float c[4] = {c0.x, c0.y, c0.z, c0.w};
    {
        h4 hh;
        hh[0] = (_Float16)h0.x; hh[1] = (_Float16)h0.y;
        hh[2] = (_Float16)h0.z; hh[3] = (_Float16)h0.w;
        *(h4*)&hpl(sm, 0, l15)[un] = hh;
    }

    const bool wr = (Hout != nullptr);
    float* hob = wr ? (Hout + ((size_t)(b0 + l15) * 512 + t0) * 128 + un) : nullptr;

    // pre-gate stream: ONE pointer, 4 dwordx4 with imm offsets g*512B
    const float* pp = P + (size_t)(b0 + l15) * TC * 512 + un;
    f32x4 pcA[4], pcB[4];
#pragma unroll
    for (int g = 0; g < 4; ++g) pcA[g] = *(const f32x4*)(pp + g * 128);
#pragma unroll
    for (int g = 0; g < 4; ++g) pcB[g] = *(const f32x4*)(pp + 512 + g * 128);
    pp += 1024;                            // points at t=2

    lds_barrier();

    for (int tl = 0; tl < TC; tl += 2) {
        rec_step<0>(sm, wh, pcA, pp, hob, wr, false, c, Sh, Sc, l15, quad, un);
        rec_step<1>(sm, wh, pcB, pp, hob, wr, (tl + 2 == TC), c, Sh, Sc, l15, quad, un);
    }
}

// ---------------------------------------------------------------------------
// K5: fused pipeline stage (multi-launch). Blocks 0-15: rec0 chunk k.
// 16-31: rec1 chunk k-2. Rest: MFMA pre-gate GEMMs (pre0 k+1, pre1 k-1).
// 80 KB LDS -> 1 block/CU: rec blocks own their CUs exclusively.
// ---------------------------------------------------------------------------
__global__ __launch_bounds__(512, 1) void k_fused(
        const float* __restrict__ X,    const float* __restrict__ H0,
        const float* __restrict__ Wih0, const float* __restrict__ Wih1,
        const float* __restrict__ bih0, const float* __restrict__ bhh0,
        const float* __restrict__ bih1, const float* __restrict__ bhh1,
        const float* __restrict__ Whh0, const float* __restrict__ Whh1,
        const float* __restrict__ P0r, float* __restrict__ P0w,
        const float* __restrict__ P1r, float* __restrict__ P1w,
        float* __restrict__ S0, float* __restrict__ S1, float* __restrict__ H0out,
        int tr0, int tr1, int tp0, int tp1,
        int v_rec0, int v_rec1, int v_pre0, int v_pre1,
        int TC, int tcs) {
    __shared__ float smem[20480];   // 80 KB -> 1 block/CU (CU isolation)
    const int bid = blockIdx.x;
    if (bid < 16) {
        if (v_rec0) rec_body(P0r, Whh0, S0, H0out, tr0, TC, bid, smem);
        return;
    }
    if (bid < 32) {
        if (v_rec1) rec_body(P1r, Whh1, S1, nullptr, tr1, TC, bid - 16, smem);
        return;
    }
    int gb = bid - 32;
    const int npre = 8 * TC;        // (256*TC/128) m-tiles * 4 n-tiles
    if (gb < npre) {
        if (v_pre0) pregemm_mfma<64>(X, Wih0, bih0, bhh0, P0w, tp0, tcs, gb, smem);
        return;
    }
    gb -= npre;
    if (v_pre1) pregemm_mfma<128>(H0, Wih1, bih1, bhh1, P1w, tp1, tcs, gb, smem);
}

// ---------------------------------------------------------------------------
// K6: tail head: out = tanh(tanh(h1_last) @ W2^T + b2) @ W3^T + b3
// ---------------------------------------------------------------------------
__global__ __launch_bounds__(64) void k_tail(const float* __restrict__ Hs,
                                             const float* __restrict__ W2,
                                             const float* __restrict__ b2,
                                             const float* __restrict__ W3,
                                             const float* __restrict__ b3,
                                             float* __restrict__ out) {
    __shared__ float last[128], l2s[64];
    const int b = blockIdx.x, tid = threadIdx.x;
    last[tid]      = ftanh(Hs[(size_t)b * 128 + tid]);
    last[tid + 64] = ftanh(Hs[(size_t)b * 128 + 64 + tid]);
    __syncthreads();
    float acc = b2[tid];
#pragma unroll 4
    for (int j = 0; j < 128; ++j) acc = fmaf(W2[(size_t)tid * 128 + j], last[j], acc);
    l2s[tid] = ftanh(acc);
    __syncthreads();
    if (tid < 32) {
        float a2 = b3[tid];
#pragma unroll 4
        for (int o = 0; o < 64; ++o) a2 = fmaf(W3[(size_t)tid * 64 + o], l2s[o], a2);
        out[(size_t)b * 32 + tid] = a2;
    }
}

// ---------------------------------------------------------------------------
extern "C" void kernel_launch(void* const* d_in, const int* in_sizes, int n_in,
                              void* d_out, int out_size, void* d_ws, size_t ws_size,
                              hipStream_t stream) {
    (void)in_sizes; (void)n_in; (void)out_size;
    const float* inp  = (const float*)d_in[0];
    const float* akey = (const float*)d_in[1];
    const float* aval = (const float*)d_in[2];
    const float* W1   = (const float*)d_in[3];
    const float* b1   = (const float*)d_in[4];
    const float* Wih0 = (const float*)d_in[5];
    const float* Whh0 = (const float*)d_in[6];
    const float* bih0 = (const float*)d_in[7];
    const float* bhh0 = (const float*)d_in[8];
    const float* Wih1 = (const float*)d_in[9];
    const float* Whh1 = (const float*)d_in[10];
    const float* bih1 = (const float*)d_in[11];
    const float* bhh1 = (const float*)d_in[12];
    const float* W2   = (const float*)d_in[13];
    const float* b2   = (const float*)d_in[14];
    const float* W3   = (const float*)d_in[15];
    const float* b3   = (const float*)d_in[16];

    float* ws   = (float*)d_ws;
    float* dist = ws;                       // 2,097,152
    float* hist = dist + 2097152;           //   139,264
    float* X    = hist + 139264;            // 8,388,608 + 64 pad
    float* S0   = X + 8388672;              //    65,536 (h then c)
    float* S1   = S0 + 65536;               //    65,536
    float* H0   = S1 + 65536;               // 16,777,216  (h0, [b][512][128])
    float* PB   = H0 + 16777216;            // 4 P buffers
    const size_t fixed = (size_t)(PB - ws);

    // TC=32 (TC=16 regressed: per-dispatch overhead ~6-9 us beats the saved
    // fill/drain steps). 4 P buffers + 2048-float pad (2-step prefetch).
    int TC = 16, tcs = 4;
    if ((fixed + 4ull * ((size_t)256 * 32 * 512 + 2048)) * 4 <= ws_size) { TC = 32; tcs = 5; }
    const size_t pchunk = (size_t)256 * TC * 512 + 2048;
    float* P0b[2] = {PB, PB + pchunk};
    float* P1b[2] = {PB + 2 * pchunk, PB + 3 * pchunk};

    k_distM<<<dim3(128, 4), 256, 0, stream>>>(inp, akey, dist);
    k_softmax<<<256, 512, 0, stream>>>(dist);
    hipMemsetAsync(hist, 0, 139264 * 4, stream);
    k_histM<<<dim3(9, 4, 16), 256, 0, stream>>>(dist, aval, hist);
    k_xfeat<<<dim3(4, 256), 256, 0, stream>>>(inp, hist, W1, b1, X);
    hipMemsetAsync(S0, 0, (size_t)2 * 65536 * 4, stream);  // S0+S1 contiguous

    const int NC = 512 / TC;
    const int nblocks = 32 + 16 * TC;   // 32 rec + 8*TC pre0 + 8*TC pre1
    for (int k = -1; k <= NC + 1; ++k) {
        int v_rec0 = (k >= 0 && k < NC);
        int v_rec1 = (k >= 2 && k < NC + 2);
        int v_pre0 = (k + 1 >= 0 && k + 1 < NC);
        int v_pre1 = (k - 1 >= 0 && k - 1 < NC);
        if (!(v_rec0 | v_rec1 | v_pre0 | v_pre1)) continue;
        const float* P0r = P0b[k & 1];
        float*       P0w = P0b[(k + 1) & 1];
        const float* P1r = P1b[k & 1];
        float*       P1w = P1b[(k + 1) & 1];
        k_fused<<<nblocks, 512, 0, stream>>>(
            X, H0, Wih0, Wih1, bih0, bhh0, bih1, bhh1, Whh0, Whh1,
            P0r, P0w, P1r, P1w, S0, S1, H0,
            k * TC, (k - 2) * TC, (k + 1) * TC, (k - 1) * TC,
            v_rec0, v_rec1, v_pre0, v_pre1, TC, tcs);
    }
    k_tail<<<256, 64, 0, stream>>>(S1, W2, b2, W3, b3, (float*)d_out);
}